// Round 7
// baseline (297.633 us; speedup 1.0000x reference)
//
#include <hip/hip_runtime.h>
#include <hip/hip_bf16.h>
#include <math.h>

// Problem constants: B=2, L=512, D=1024, H=16, DH=64. N = B*L = 1024.
// Single mega-kernel: 256 blocks (= #CUs, 1/CU guaranteed resident) x 256 thr,
// phases separated by hand-rolled device-scope barriers.

typedef unsigned short ushort_t;
typedef __attribute__((ext_vector_type(8))) short bf16x8;
typedef __attribute__((ext_vector_type(4))) float f32x4;

__device__ __forceinline__ float sigmoidf_(float z) { return 1.f / (1.f + expf(-z)); }

__device__ __forceinline__ ushort_t f2bf(float f) {
    __hip_bfloat16 h = __float2bfloat16(f);
    return *reinterpret_cast<ushort_t*>(&h);
}

__device__ __forceinline__ float bf2f(ushort_t u) {
    union { unsigned int i; float f; } v;
    v.i = ((unsigned int)u) << 16;
    return v.f;
}

__device__ __forceinline__ void gl16(const void* g, void* l) {
    __builtin_amdgcn_global_load_lds(
        (const __attribute__((address_space(1))) unsigned int*)g,
        (__attribute__((address_space(3))) unsigned int*)l, 16, 0, 0);
}

// device-scope barrier: monotonic counter, one arrival per block.
__device__ __forceinline__ void gbar(unsigned int* cnt, unsigned int target) {
    __syncthreads();
    if (threadIdx.x == 0) {
        __threadfence();   // release our writes device-wide
        __hip_atomic_fetch_add(cnt, 1u, __ATOMIC_ACQ_REL, __HIP_MEMORY_SCOPE_AGENT);
        while (__hip_atomic_load(cnt, __ATOMIC_ACQUIRE, __HIP_MEMORY_SCOPE_AGENT) < target)
            __builtin_amdgcn_s_sleep(2);
    }
    __syncthreads();
    __threadfence();       // acquire: invalidate caches for fresh reads
}

struct MegaArgs {
    const float *x, *q1w, *q1b, *k1w, *k1b, *k2w, *k2bias, *gww, *gwb, *sww, *swb, *cpw, *cpb;
    float *out;
    float *O1, *dS0, *dS1, *gc, *ab;
    unsigned int *cnt;
    ushort_t *xb, *qb, *kb, *k2q, *wqT, *wkT, *wcT, *wpT, *ytb;
};

__global__ __launch_bounds__(256) void mega(MegaArgs A) {
    const int flat = blockIdx.x;
    const int tid = threadIdx.x;
    const int w = tid >> 6, lane = tid & 63;
    const int l15 = lane & 15, lq = lane >> 4;

    __shared__ __align__(16) char smem[65536];
    typedef ushort_t row72[72];

    // ============ phase 0: weight transpose-cvt + x cvt ============
    {
        row72* T = (row72*)smem;
        const float* Ws[4] = {A.q1w, A.k1w, A.k2w, A.cpw};
        ushort_t* Ts[4] = {A.wqT, A.wkT, A.wcT, A.wpT};
        const int k0 = (flat >> 4) * 64, n0 = (flat & 15) * 64;
#pragma unroll
        for (int wi = 0; wi < 4; ++wi) {
            if (wi) __syncthreads();
            const float* W = Ws[wi];
            ushort_t* WT = Ts[wi];
#pragma unroll
            for (int it = 0; it < 4; ++it) {
                const int idx = tid + it * 256;
                const int r = idx >> 4, c4 = (idx & 15) * 4;
                float4 v = *reinterpret_cast<const float4*>(W + (size_t)(k0 + r) * 1024 + n0 + c4);
                T[r][c4 + 0] = f2bf(v.x); T[r][c4 + 1] = f2bf(v.y);
                T[r][c4 + 2] = f2bf(v.z); T[r][c4 + 3] = f2bf(v.w);
            }
            __syncthreads();
            const int n = tid >> 2, kq = (tid & 3) * 16;
            union { uint4 v[2]; ushort_t u[16]; } pk;
#pragma unroll
            for (int j2 = 0; j2 < 16; ++j2) pk.u[j2] = T[kq + j2][n];
            *reinterpret_cast<uint4*>(WT + (size_t)(n0 + n) * 1024 + k0 + kq) = pk.v[0];
            *reinterpret_cast<uint4*>(WT + (size_t)(n0 + n) * 1024 + k0 + kq + 8) = pk.v[1];
        }
#pragma unroll
        for (int q = 0; q < 2; ++q) {
            const int off = ((flat * 2 + q) * 256 + tid) * 8;
            float4 a0 = *reinterpret_cast<const float4*>(A.x + off);
            float4 b0 = *reinterpret_cast<const float4*>(A.x + off + 4);
            union { uint4 v; ushort_t u[8]; } pk;
            pk.u[0] = f2bf(a0.x); pk.u[1] = f2bf(a0.y); pk.u[2] = f2bf(a0.z); pk.u[3] = f2bf(a0.w);
            pk.u[4] = f2bf(b0.x); pk.u[5] = f2bf(b0.y); pk.u[6] = f2bf(b0.z); pk.u[7] = f2bf(b0.w);
            *reinterpret_cast<uint4*>(A.xb + off) = pk.v;
        }
    }
    gbar(A.cnt, 256);

    // ============ phase 1: Q/K/K2 GEMM (A-tile shared across 3 weights) ============
    {
        char* AsB = smem;           // 8 KB
        char* BsB = smem + 8192;    // 3 x 8 KB
        const int m0 = (flat >> 4) * 64, n0 = (flat & 15) * 64;
        const ushort_t* Wt0 = A.wqT;
        const ushort_t* Wt1 = A.wkT;
        const ushort_t* Wt2 = A.wcT;
        f32x4 acc0[4], acc1[4], acc2[4];
#pragma unroll
        for (int i = 0; i < 4; ++i) {
            acc0[i] = (f32x4){0.f, 0.f, 0.f, 0.f};
            acc1[i] = (f32x4){0.f, 0.f, 0.f, 0.f};
            acc2[i] = (f32x4){0.f, 0.f, 0.f, 0.f};
        }
        for (int k0 = 0; k0 < 1024; k0 += 64) {
            __syncthreads();
#pragma unroll
            for (int is = 0; is < 2; ++is) {
                const int p = tid * 16 + is * 4096;
                const int row = p >> 7;
                const int scb = (p & 127) ^ ((row & 7) << 4);
                gl16((const char*)A.xb + (((size_t)(m0 + row)) << 11) + (k0 << 1) + scb,
                     AsB + is * 4096 + w * 1024);
                gl16((const char*)Wt0 + (((size_t)(n0 + row)) << 11) + (k0 << 1) + scb,
                     BsB + is * 4096 + w * 1024);
                gl16((const char*)Wt1 + (((size_t)(n0 + row)) << 11) + (k0 << 1) + scb,
                     BsB + 8192 + is * 4096 + w * 1024);
                gl16((const char*)Wt2 + (((size_t)(n0 + row)) << 11) + (k0 << 1) + scb,
                     BsB + 16384 + is * 4096 + w * 1024);
            }
            __syncthreads();
#pragma unroll
            for (int kk = 0; kk < 64; kk += 32) {
                const int cb = (kk + 8 * lq) * 2;
                const int ra = 16 * w + l15;
                bf16x8 a = *reinterpret_cast<const bf16x8*>(AsB + ra * 128 + (cb ^ ((ra & 7) << 4)));
#pragma unroll
                for (int nt = 0; nt < 4; ++nt) {
                    const int rb = 16 * nt + l15;
                    const int boff = rb * 128 + (cb ^ ((rb & 7) << 4));
                    bf16x8 b0v = *reinterpret_cast<const bf16x8*>(BsB + boff);
                    bf16x8 b1v = *reinterpret_cast<const bf16x8*>(BsB + 8192 + boff);
                    bf16x8 b2v = *reinterpret_cast<const bf16x8*>(BsB + 16384 + boff);
                    acc0[nt] = __builtin_amdgcn_mfma_f32_16x16x32_bf16(a, b0v, acc0[nt], 0, 0, 0);
                    acc1[nt] = __builtin_amdgcn_mfma_f32_16x16x32_bf16(a, b1v, acc1[nt], 0, 0, 0);
                    acc2[nt] = __builtin_amdgcn_mfma_f32_16x16x32_bf16(a, b2v, acc2[nt], 0, 0, 0);
                }
            }
        }
#pragma unroll
        for (int nt = 0; nt < 4; ++nt) {
            const int col = n0 + 16 * nt + l15;
            const float bq = A.q1b[col], bk = A.k1b[col], bc = A.k2bias[col];
#pragma unroll
            for (int r = 0; r < 4; ++r) {
                const int row = m0 + 16 * w + 4 * lq + r;
                A.qb[(size_t)row * 1024 + col] = f2bf(acc0[nt][r] + bq);
                A.kb[(size_t)row * 1024 + col] = f2bf(acc1[nt][r] + bk);
                A.k2q[(size_t)row * 1024 + col] = f2bf(sigmoidf_((acc2[nt][r] + bc) * 6.25e-4f));
            }
        }
    }
    gbar(A.cnt, 512);

    // ============ phase 2: gate scan + dS0 ============
    {
        const int j = flat & 7, bh = flat >> 3;
        const int b = bh >> 4, h = bh & 15;
        float* gwl = (float*)smem;
        float* swl = gwl + 64;
        float* ctot = swl + 64;
        float* abl = ctot + 8;
        row72* KT = (row72*)(smem + 1024);
        row72* VT = (row72*)(smem + 1024 + 9216);
        const size_t base = (size_t)(b * 512) * 1024 + h * 64;

        if (tid < 64) gwl[tid] = A.gww[tid];
        else if (tid < 128) swl[tid - 64] = A.sww[tid - 64];
        __syncthreads();
        const float gwb = A.gwb[0], swb = A.swb[0];

        const int T = (j + 1) * 64;
        float ps_own = 0.f, dk_own = 0.f;
        for (int i = 0; i * 256 < T; ++i) {
            const int t = i * 256 + tid;
            const int cseg = i * 4 + w;
            if (cseg <= j) {
                const float* xr = A.x + base + (size_t)t * 1024;
                float dg = 0.f;
#pragma unroll
                for (int d = 0; d < 64; d += 4) {
                    float4 xv = *reinterpret_cast<const float4*>(xr + d);
                    dg += xv.x * gwl[d] + xv.y * gwl[d + 1] + xv.z * gwl[d + 2] + xv.w * gwl[d + 3];
                }
                float dk = 0.f;
                if (cseg == j) {
                    const ushort_t* kr = A.kb + base + (size_t)t * 1024;
#pragma unroll
                    for (int d = 0; d < 64; d += 8) {
                        union { uint4 v; ushort_t u[8]; } kv;
                        kv.v = *reinterpret_cast<const uint4*>(kr + d);
#pragma unroll
                        for (int q = 0; q < 8; ++q) dk += bf2f(kv.u[q]) * swl[d + q];
                    }
                }
                const float g = sigmoidf_(dg + gwb);
                float ps = logf(fmaxf(g, 1e-6f));
#pragma unroll
                for (int off = 1; off < 64; off <<= 1) {
                    float v = __shfl_up(ps, off, 64);
                    if (lane >= off) ps += v;
                }
                if (lane == 63) ctot[cseg] = ps;
                if (cseg == j) { ps_own = ps; dk_own = dk; }
            }
        }
        __syncthreads();
        if (w == (j & 3)) {
            float coff = 0.f;
            for (int cc = 0; cc < j; ++cc) coff += ctot[cc];
            const float lsum = coff + ps_own;
            const float Gc = expf(fminf(fmaxf(lsum, -30.f), 30.f)) + 1e-6f;
            const float z = dk_own + swb;
            const float a = z * sigmoidf_(z) / Gc;
            abl[lane] = a;
            A.gc[bh * 512 + j * 64 + lane] = Gc;
            A.ab[bh * 512 + j * 64 + lane] = a;
        }
        __syncthreads();

#pragma unroll
        for (int it = 0; it < 4; ++it) {
            const int idx = tid + it * 256;
            const int rr = idx >> 4;
            const int c4 = (idx & 15) << 2;
            const int tau = j * 64 + rr;
            ushort4 kv = *reinterpret_cast<const ushort4*>(A.kb + base + (size_t)tau * 1024 + c4);
            float4 xv = *reinterpret_cast<const float4*>(A.x + base + (size_t)tau * 1024 + c4);
            const float a = abl[rr];
            KT[c4 + 0][rr] = kv.x; KT[c4 + 1][rr] = kv.y;
            KT[c4 + 2][rr] = kv.z; KT[c4 + 3][rr] = kv.w;
            VT[c4 + 0][rr] = f2bf(a * xv.x); VT[c4 + 1][rr] = f2bf(a * xv.y);
            VT[c4 + 2][rr] = f2bf(a * xv.z); VT[c4 + 3][rr] = f2bf(a * xv.w);
        }
        __syncthreads();

        f32x4 st[4];
#pragma unroll
        for (int n = 0; n < 4; ++n) st[n] = (f32x4){0.f, 0.f, 0.f, 0.f};
#pragma unroll
        for (int kk = 0; kk < 64; kk += 32) {
            bf16x8 ak = *reinterpret_cast<const bf16x8*>(&KT[16 * w + l15][kk + 8 * lq]);
#pragma unroll
            for (int n = 0; n < 4; ++n) {
                bf16x8 vb = *reinterpret_cast<const bf16x8*>(&VT[16 * n + l15][kk + 8 * lq]);
                st[n] = __builtin_amdgcn_mfma_f32_16x16x32_bf16(ak, vb, st[n], 0, 0, 0);
            }
        }
        float* o = A.dS0 + (size_t)(bh * 8 + j) * 4096;
#pragma unroll
        for (int n = 0; n < 4; ++n)
#pragma unroll
            for (int r = 0; r < 4; ++r)
                o[(16 * w + 4 * lq + r) * 64 + 16 * n + l15] = st[n][r];
    }
    gbar(A.cnt, 768);

    // ============ phase 3: GLA output + dS1 ============
    {
        const int rt = flat & 7, bh = flat >> 3;
        const int b = bh >> 4, h = bh & 15;
        const int c0 = rt * 64;
        row72* Qs  = (row72*)(smem);
        row72* Ks  = (row72*)(smem + 9216);
        row72* VT  = (row72*)(smem + 18432);
        row72* K2T = (row72*)(smem + 27648);
        row72* ET  = (row72*)(smem + 36864);
        row72* Ps  = (row72*)(smem + 46080);
        row72* SBt = (row72*)(smem + 55296);
        float* av  = (float*)(smem + 64512);
        float* gcv = av + 64;
        const size_t base = (size_t)(b * 512) * 1024 + h * 64;

#pragma unroll
        for (int it = 0; it < 2; ++it) {
            const int idx = tid + it * 256;
            const int rr = idx >> 3;
            const int c8 = (idx & 7) << 3;
            const int tau = c0 + rr;
            *reinterpret_cast<uint4*>(&Qs[rr][c8]) =
                *reinterpret_cast<const uint4*>(A.qb + base + (size_t)tau * 1024 + c8);
            *reinterpret_cast<uint4*>(&Ks[rr][c8]) =
                *reinterpret_cast<const uint4*>(A.kb + base + (size_t)tau * 1024 + c8);
        }
#pragma unroll
        for (int it = 0; it < 4; ++it) {
            const int idx = tid + it * 256;
            const int rr = idx >> 4;
            const int c4 = (idx & 15) << 2;
            const int tau = c0 + rr;
            float4 xv = *reinterpret_cast<const float4*>(A.x + base + (size_t)tau * 1024 + c4);
            VT[c4 + 0][rr] = f2bf(xv.x); VT[c4 + 1][rr] = f2bf(xv.y);
            VT[c4 + 2][rr] = f2bf(xv.z); VT[c4 + 3][rr] = f2bf(xv.w);
            if (tau <= 510) {
                ushort4 cv = *reinterpret_cast<const ushort4*>(A.k2q + base + (size_t)tau * 1024 + c4);
                K2T[c4 + 0][rr] = cv.x; K2T[c4 + 1][rr] = cv.y;
                K2T[c4 + 2][rr] = cv.z; K2T[c4 + 3][rr] = cv.w;
            } else {
                K2T[c4 + 0][rr] = 0; K2T[c4 + 1][rr] = 0;
                K2T[c4 + 2][rr] = 0; K2T[c4 + 3][rr] = 0;
            }
        }
        if (tid < 64) av[tid] = A.ab[bh * 512 + c0 + tid];
        else if (tid < 128) gcv[tid - 64] = A.gc[bh * 512 + c0 + tid - 64];

#pragma unroll
        for (int ii = 0; ii < 4; ++ii) {
            const int flat2 = tid * 16 + ii * 4;
            float4 s = {0.f, 0.f, 0.f, 0.f};
            for (int jj = 0; jj < rt; ++jj) {
                float4 v = *reinterpret_cast<const float4*>(A.dS0 + (size_t)(bh * 8 + jj) * 4096 + flat2);
                s.x += v.x; s.y += v.y; s.z += v.z; s.w += v.w;
            }
            const int d = flat2 >> 6, e = flat2 & 63;
            SBt[e + 0][d] = f2bf(s.x); SBt[e + 1][d] = f2bf(s.y);
            SBt[e + 2][d] = f2bf(s.z); SBt[e + 3][d] = f2bf(s.w);
        }
        __syncthreads();

        f32x4 sc[4];
#pragma unroll
        for (int n = 0; n < 4; ++n) sc[n] = (f32x4){0.f, 0.f, 0.f, 0.f};
#pragma unroll
        for (int kk = 0; kk < 64; kk += 32) {
            bf16x8 aq = *reinterpret_cast<const bf16x8*>(&Qs[16 * w + l15][kk + 8 * lq]);
#pragma unroll
            for (int n = 0; n < 4; ++n) {
                bf16x8 bb = *reinterpret_cast<const bf16x8*>(&Ks[16 * n + l15][kk + 8 * lq]);
                sc[n] = __builtin_amdgcn_mfma_f32_16x16x32_bf16(aq, bb, sc[n], 0, 0, 0);
            }
        }
#pragma unroll
        for (int n = 0; n < 4; ++n) {
            const int cl = 16 * n + l15;
#pragma unroll
            for (int r = 0; r < 4; ++r) {
                const int tl = 16 * w + 4 * lq + r;
                Ps[tl][cl] = f2bf(cl <= tl ? sc[n][r] * av[cl] : 0.f);
            }
        }
        __syncthreads();

        f32x4 oc[4];
#pragma unroll
        for (int n = 0; n < 4; ++n) oc[n] = (f32x4){0.f, 0.f, 0.f, 0.f};
#pragma unroll
        for (int kk = 0; kk < 64; kk += 32) {
            bf16x8 aq = *reinterpret_cast<const bf16x8*>(&Qs[16 * w + l15][kk + 8 * lq]);
            bf16x8 ap = *reinterpret_cast<const bf16x8*>(&Ps[16 * w + l15][kk + 8 * lq]);
#pragma unroll
            for (int n = 0; n < 4; ++n) {
                bf16x8 sb = *reinterpret_cast<const bf16x8*>(&SBt[16 * n + l15][kk + 8 * lq]);
                oc[n] = __builtin_amdgcn_mfma_f32_16x16x32_bf16(aq, sb, oc[n], 0, 0, 0);
                bf16x8 vb = *reinterpret_cast<const bf16x8*>(&VT[16 * n + l15][kk + 8 * lq]);
                oc[n] = __builtin_amdgcn_mfma_f32_16x16x32_bf16(ap, vb, oc[n], 0, 0, 0);
            }
        }

#pragma unroll
        for (int n = 0; n < 4; ++n) {
            const int e = 16 * n + l15;
#pragma unroll
            for (int r = 0; r < 4; ++r) {
                const int tl = 16 * w + 4 * lq + r;
                const int tau = c0 + tl;
                const float val = gcv[tl] * oc[n][r];
                A.O1[base + (size_t)tau * 1024 + e] = val;
                float ev = 0.f;
                if (tau <= 510) ev = A.x[base + (size_t)(tau + 1) * 1024 + e] - val;
                ET[e][tl] = f2bf(ev);
            }
        }
        __syncthreads();

        f32x4 st[4];
#pragma unroll
        for (int n = 0; n < 4; ++n) st[n] = (f32x4){0.f, 0.f, 0.f, 0.f};
#pragma unroll
        for (int kk = 0; kk < 64; kk += 32) {
            bf16x8 ak = *reinterpret_cast<const bf16x8*>(&K2T[16 * w + l15][kk + 8 * lq]);
#pragma unroll
            for (int n = 0; n < 4; ++n) {
                bf16x8 eb = *reinterpret_cast<const bf16x8*>(&ET[16 * n + l15][kk + 8 * lq]);
                st[n] = __builtin_amdgcn_mfma_f32_16x16x32_bf16(ak, eb, st[n], 0, 0, 0);
            }
        }
        float* o = A.dS1 + (size_t)(bh * 8 + rt) * 4096;
#pragma unroll
        for (int n = 0; n < 4; ++n)
#pragma unroll
            for (int r = 0; r < 4; ++r)
                o[(16 * w + 4 * lq + r) * 64 + 16 * n + l15] = st[n][r];
    }
    gbar(A.cnt, 1024);

    // ============ phase 4: MA output + y (bf16) ============
    {
        const int rt = flat & 7, bh = flat >> 3;
        const int b = bh >> 4, h = bh & 15;
        const int c0 = rt * 64;
        row72* Q2s = (row72*)(smem);
        row72* K2s = (row72*)(smem + 9216);
        row72* ET  = (row72*)(smem + 18432);
        row72* Ps  = (row72*)(smem + 27648);
        row72* SBt = (row72*)(smem + 36864);
        const size_t base = (size_t)(b * 512) * 1024 + h * 64;

#pragma unroll
        for (int it = 0; it < 2; ++it) {
            const int idx = tid + it * 256;
            const int rr = idx >> 3;
            const int c8 = (idx & 7) << 3;
            const int tau = c0 + rr;
            union { uint4 v; ushort_t u[8]; } qv, qo;
            qv.v = *reinterpret_cast<const uint4*>(A.qb + base + (size_t)tau * 1024 + c8);
#pragma unroll
            for (int q = 0; q < 8; ++q) {
                const float f = bf2f(qv.u[q]);
                qo.u[q] = f2bf((f < 0.f ? f : 0.02f * f) * 0.125f);
            }
            *reinterpret_cast<uint4*>(&Q2s[rr][c8]) = qo.v;
            if (tau <= 510) {
                *reinterpret_cast<uint4*>(&K2s[rr][c8]) =
                    *reinterpret_cast<const uint4*>(A.k2q + base + (size_t)tau * 1024 + c8);
            } else {
                *reinterpret_cast<uint4*>(&K2s[rr][c8]) = (uint4){0, 0, 0, 0};
            }
        }
#pragma unroll
        for (int it = 0; it < 4; ++it) {
            const int idx = tid + it * 256;
            const int rr = idx >> 4;
            const int c4 = (idx & 15) << 2;
            const int tau = c0 + rr;
            if (tau <= 510) {
                float4 xv = *reinterpret_cast<const float4*>(A.x + base + (size_t)(tau + 1) * 1024 + c4);
                float4 ov = *reinterpret_cast<const float4*>(A.O1 + base + (size_t)tau * 1024 + c4);
                ET[c4 + 0][rr] = f2bf(xv.x - ov.x); ET[c4 + 1][rr] = f2bf(xv.y - ov.y);
                ET[c4 + 2][rr] = f2bf(xv.z - ov.z); ET[c4 + 3][rr] = f2bf(xv.w - ov.w);
            } else {
                ET[c4 + 0][rr] = 0; ET[c4 + 1][rr] = 0; ET[c4 + 2][rr] = 0; ET[c4 + 3][rr] = 0;
            }
        }
#pragma unroll
        for (int ii = 0; ii < 4; ++ii) {
            const int flat2 = tid * 16 + ii * 4;
            float4 s = {0.f, 0.f, 0.f, 0.f};
            for (int jj = 0; jj < rt; ++jj) {
                float4 v = *reinterpret_cast<const float4*>(A.dS1 + (size_t)(bh * 8 + jj) * 4096 + flat2);
                s.x += v.x; s.y += v.y; s.z += v.z; s.w += v.w;
            }
            const int d = flat2 >> 6, e = flat2 & 63;
            SBt[e + 0][d] = f2bf(s.x); SBt[e + 1][d] = f2bf(s.y);
            SBt[e + 2][d] = f2bf(s.z); SBt[e + 3][d] = f2bf(s.w);
        }
        __syncthreads();

        f32x4 sc[4];
#pragma unroll
        for (int n = 0; n < 4; ++n) sc[n] = (f32x4){0.f, 0.f, 0.f, 0.f};
#pragma unroll
        for (int kk = 0; kk < 64; kk += 32) {
            bf16x8 aq = *reinterpret_cast<const bf16x8*>(&Q2s[16 * w + l15][kk + 8 * lq]);
#pragma unroll
            for (int n = 0; n < 4; ++n) {
                bf16x8 bb = *reinterpret_cast<const bf16x8*>(&K2s[16 * n + l15][kk + 8 * lq]);
                sc[n] = __builtin_amdgcn_mfma_f32_16x16x32_bf16(aq, bb, sc[n], 0, 0, 0);
            }
        }
#pragma unroll
        for (int n = 0; n < 4; ++n) {
            const int cl = 16 * n + l15;
#pragma unroll
            for (int r = 0; r < 4; ++r) {
                const int tl = 16 * w + 4 * lq + r;
                Ps[tl][cl] = f2bf(cl <= tl ? sc[n][r] : 0.f);
            }
        }
        __syncthreads();

        f32x4 oc[4];
#pragma unroll
        for (int n = 0; n < 4; ++n) oc[n] = (f32x4){0.f, 0.f, 0.f, 0.f};
#pragma unroll
        for (int kk = 0; kk < 64; kk += 32) {
            bf16x8 aq = *reinterpret_cast<const bf16x8*>(&Q2s[16 * w + l15][kk + 8 * lq]);
            bf16x8 ap = *reinterpret_cast<const bf16x8*>(&Ps[16 * w + l15][kk + 8 * lq]);
#pragma unroll
            for (int n = 0; n < 4; ++n) {
                bf16x8 sb = *reinterpret_cast<const bf16x8*>(&SBt[16 * n + l15][kk + 8 * lq]);
                oc[n] = __builtin_amdgcn_mfma_f32_16x16x32_bf16(aq, sb, oc[n], 0, 0, 0);
                bf16x8 eb = *reinterpret_cast<const bf16x8*>(&ET[16 * n + l15][kk + 8 * lq]);
                oc[n] = __builtin_amdgcn_mfma_f32_16x16x32_bf16(ap, eb, oc[n], 0, 0, 0);
            }
        }

#pragma unroll
        for (int n = 0; n < 4; ++n) {
            const int e = 16 * n + l15;
#pragma unroll
            for (int r = 0; r < 4; ++r) {
                const int tp = c0 + 16 * w + 4 * lq + r;
                if (tp <= 510) {
                    A.ytb[(size_t)(b * 512 + tp + 1) * 1024 + h * 64 + e] =
                        f2bf(A.O1[base + (size_t)(tp + 1) * 1024 + e] + oc[n][r]);
                }
            }
        }
        if (rt == 0 && tid < 64)
            A.ytb[(size_t)(b * 512) * 1024 + h * 64 + tid] = f2bf(A.O1[base + tid]);
    }
    gbar(A.cnt, 1280);

    // ============ phase 5: final projection GEMM ============
    {
        char* AsB = smem;
        char* BsB = smem + 8192;
        const int m0 = (flat >> 4) * 64, n0 = (flat & 15) * 64;
        f32x4 acc[4];
#pragma unroll
        for (int i = 0; i < 4; ++i) acc[i] = (f32x4){0.f, 0.f, 0.f, 0.f};
        for (int k0 = 0; k0 < 1024; k0 += 64) {
            __syncthreads();
#pragma unroll
            for (int is = 0; is < 2; ++is) {
                const int p = tid * 16 + is * 4096;
                const int row = p >> 7;
                const int scb = (p & 127) ^ ((row & 7) << 4);
                gl16((const char*)A.ytb + (((size_t)(m0 + row)) << 11) + (k0 << 1) + scb,
                     AsB + is * 4096 + w * 1024);
                gl16((const char*)A.wpT + (((size_t)(n0 + row)) << 11) + (k0 << 1) + scb,
                     BsB + is * 4096 + w * 1024);
            }
            __syncthreads();
#pragma unroll
            for (int kk = 0; kk < 64; kk += 32) {
                const int cb = (kk + 8 * lq) * 2;
                const int ra = 16 * w + l15;
                bf16x8 a = *reinterpret_cast<const bf16x8*>(AsB + ra * 128 + (cb ^ ((ra & 7) << 4)));
#pragma unroll
                for (int nt = 0; nt < 4; ++nt) {
                    const int rb = 16 * nt + l15;
                    bf16x8 b = *reinterpret_cast<const bf16x8*>(BsB + rb * 128 + (cb ^ ((rb & 7) << 4)));
                    acc[nt] = __builtin_amdgcn_mfma_f32_16x16x32_bf16(a, b, acc[nt], 0, 0, 0);
                }
            }
        }
#pragma unroll
        for (int nt = 0; nt < 4; ++nt) {
            const int col = n0 + 16 * nt + l15;
            const float bcol = A.cpb[col];
#pragma unroll
            for (int r = 0; r < 4; ++r) {
                const int row = m0 + 16 * w + 4 * lq + r;
                A.out[(size_t)row * 1024 + col] = acc[nt][r] + bcol;
            }
        }
    }
}

// ---------------------------------------------------------------------------
extern "C" void kernel_launch(void* const* d_in, const int* in_sizes, int n_in,
                              void* d_out, int out_size, void* d_ws, size_t ws_size,
                              hipStream_t stream) {
    float* ws = (float*)d_ws;
    MegaArgs a;
    a.x = (const float*)d_in[0];
    a.q1w = (const float*)d_in[1];
    a.q1b = (const float*)d_in[2];
    a.k1w = (const float*)d_in[3];
    a.k1b = (const float*)d_in[4];
    a.k2w = (const float*)d_in[5];
    a.k2bias = (const float*)d_in[6];
    a.gww = (const float*)d_in[7];
    a.gwb = (const float*)d_in[8];
    a.sww = (const float*)d_in[9];
    a.swb = (const float*)d_in[10];
    a.cpw = (const float*)d_in[11];
    a.cpb = (const float*)d_in[12];
    a.out = (float*)d_out;

    a.O1  = ws;                 // 1,048,576 floats
    a.dS0 = ws + 1048576;       // 1,048,576
    a.dS1 = ws + 2097152;       // 1,048,576
    a.gc  = ws + 3145728;       // 16,384
    a.ab  = ws + 3162112;       // 16,384
    a.cnt = (unsigned int*)(ws + 3178496);  // 16 uints (padded to 64 floats)
    ushort_t* ub = (ushort_t*)(ws + 3178560);
    a.xb  = ub;                 // 1,048,576 ushorts each
    a.qb  = ub + 1048576;
    a.kb  = ub + 2097152;
    a.k2q = ub + 3145728;
    a.wqT = ub + 4194304;
    a.wkT = ub + 5242880;
    a.wcT = ub + 6291456;
    a.wpT = ub + 7340032;
    a.ytb = ub + 8388608;
    // total ~31.6 MB of d_ws

    hipMemsetAsync(a.cnt, 0, 64, stream);
    mega<<<256, 256, 0, stream>>>(a);
}

// Round 8
// 83.644 us; speedup vs baseline: 3.5583x; 3.5583x over previous
//
#include <hip/hip_runtime.h>
#include <hip/hip_bf16.h>
#include <math.h>

// Problem constants: B=2, L=512, D=1024, H=16, DH=64. N = B*L = 1024.

typedef unsigned short ushort_t;
typedef __attribute__((ext_vector_type(8))) short bf16x8;
typedef __attribute__((ext_vector_type(4))) float f32x4;

__device__ __forceinline__ float sigmoidf_(float z) { return 1.f / (1.f + expf(-z)); }

__device__ __forceinline__ ushort_t f2bf(float f) {
    __hip_bfloat16 h = __float2bfloat16(f);
    return *reinterpret_cast<ushort_t*>(&h);
}

__device__ __forceinline__ float bf2f(ushort_t u) {
    union { unsigned int i; float f; } v;
    v.i = ((unsigned int)u) << 16;
    return v.f;
}

__device__ __forceinline__ void gl16(const void* g, void* l) {
    __builtin_amdgcn_global_load_lds(
        (const __attribute__((address_space(1))) unsigned int*)g,
        (__attribute__((address_space(3))) unsigned int*)l, 16, 0, 0);
}

// ---------------------------------------------------------------------------
// cvtT: blocks 0..1023: transpose-convert 4 weights fp32[K][N] -> bf16[N][K].
//       blocks 1024..1535: convert x fp32 -> bf16.
// ---------------------------------------------------------------------------
__global__ __launch_bounds__(256) void cvtT(const float* __restrict__ xs,
                                            const float* __restrict__ w0, const float* __restrict__ w1,
                                            const float* __restrict__ w2, const float* __restrict__ w3,
                                            ushort_t* __restrict__ xd,
                                            ushort_t* __restrict__ t0, ushort_t* __restrict__ t1,
                                            ushort_t* __restrict__ t2, ushort_t* __restrict__ t3) {
    const int blk = blockIdx.x;
    const int tid = threadIdx.x;
    if (blk >= 1024) {
        const int off = ((blk - 1024) * 256 + tid) * 8;
        float4 a = *reinterpret_cast<const float4*>(xs + off);
        float4 b = *reinterpret_cast<const float4*>(xs + off + 4);
        union { uint4 v; ushort_t u[8]; } pk;
        pk.u[0] = f2bf(a.x); pk.u[1] = f2bf(a.y); pk.u[2] = f2bf(a.z); pk.u[3] = f2bf(a.w);
        pk.u[4] = f2bf(b.x); pk.u[5] = f2bf(b.y); pk.u[6] = f2bf(b.z); pk.u[7] = f2bf(b.w);
        *reinterpret_cast<uint4*>(xd + off) = pk.v;
        return;
    }
    const int wi = blk >> 8;
    const float* W = wi == 0 ? w0 : wi == 1 ? w1 : wi == 2 ? w2 : w3;
    ushort_t* WT = wi == 0 ? t0 : wi == 1 ? t1 : wi == 2 ? t2 : t3;
    const int tile = blk & 255;
    const int k0 = (tile >> 4) * 64, n0 = (tile & 15) * 64;
    __shared__ ushort_t T[64][72];
#pragma unroll
    for (int it = 0; it < 4; ++it) {
        const int idx = tid + it * 256;
        const int r = idx >> 4;
        const int c4 = (idx & 15) * 4;
        float4 v = *reinterpret_cast<const float4*>(W + (size_t)(k0 + r) * 1024 + n0 + c4);
        T[r][c4 + 0] = f2bf(v.x); T[r][c4 + 1] = f2bf(v.y);
        T[r][c4 + 2] = f2bf(v.z); T[r][c4 + 3] = f2bf(v.w);
    }
    __syncthreads();
    const int n = tid >> 2;
    const int kq = (tid & 3) * 16;
    union { uint4 v[2]; ushort_t u[16]; } pk;
#pragma unroll
    for (int j = 0; j < 16; ++j) pk.u[j] = T[kq + j][n];
    *reinterpret_cast<uint4*>(WT + (size_t)(n0 + n) * 1024 + k0 + kq) = pk.v[0];
    *reinterpret_cast<uint4*>(WT + (size_t)(n0 + n) * 1024 + k0 + kq + 8) = pk.v[1];
}

// ---------------------------------------------------------------------------
// gemm3: fused Q/K/K2 GEMM, A-tile shared across 3 weights. 256 blocks.
// Epilogue: qb=bf16(Q), q2b=bf16(leaky(Q)), kb=bf16(K), k2q=bf16(sigmoid(C2*s)).
// ---------------------------------------------------------------------------
__global__ __launch_bounds__(256) void gemm3(const ushort_t* __restrict__ Ab,
                                             const ushort_t* __restrict__ WqT,
                                             const ushort_t* __restrict__ WkT,
                                             const ushort_t* __restrict__ WcT,
                                             const float* __restrict__ bq_,
                                             const float* __restrict__ bk_,
                                             const float* __restrict__ bc_,
                                             ushort_t* __restrict__ qb,
                                             ushort_t* __restrict__ q2b,
                                             ushort_t* __restrict__ kb,
                                             ushort_t* __restrict__ k2q) {
    const int m0 = blockIdx.y * 64, n0 = blockIdx.x * 64;
    __shared__ __align__(16) char smem[32768];
    char* AsB = smem;
    char* BsB = smem + 8192;

    const int tid = threadIdx.x;
    const int w = tid >> 6, lane = tid & 63;
    const int l15 = lane & 15, lq = lane >> 4;

    f32x4 acc0[4], acc1[4], acc2[4];
#pragma unroll
    for (int i = 0; i < 4; ++i) {
        acc0[i] = (f32x4){0.f, 0.f, 0.f, 0.f};
        acc1[i] = (f32x4){0.f, 0.f, 0.f, 0.f};
        acc2[i] = (f32x4){0.f, 0.f, 0.f, 0.f};
    }

    for (int k0 = 0; k0 < 1024; k0 += 64) {
        __syncthreads();
#pragma unroll
        for (int is = 0; is < 2; ++is) {
            const int p = tid * 16 + is * 4096;
            const int row = p >> 7;
            const int scb = (p & 127) ^ ((row & 7) << 4);
            gl16((const char*)Ab + (((size_t)(m0 + row)) << 11) + (k0 << 1) + scb,
                 AsB + is * 4096 + w * 1024);
            gl16((const char*)WqT + (((size_t)(n0 + row)) << 11) + (k0 << 1) + scb,
                 BsB + is * 4096 + w * 1024);
            gl16((const char*)WkT + (((size_t)(n0 + row)) << 11) + (k0 << 1) + scb,
                 BsB + 8192 + is * 4096 + w * 1024);
            gl16((const char*)WcT + (((size_t)(n0 + row)) << 11) + (k0 << 1) + scb,
                 BsB + 16384 + is * 4096 + w * 1024);
        }
        __syncthreads();
#pragma unroll
        for (int kk = 0; kk < 64; kk += 32) {
            const int cb = (kk + 8 * lq) * 2;
            const int ra = 16 * w + l15;
            bf16x8 a = *reinterpret_cast<const bf16x8*>(AsB + ra * 128 + (cb ^ ((ra & 7) << 4)));
#pragma unroll
            for (int nt = 0; nt < 4; ++nt) {
                const int rb = 16 * nt + l15;
                const int boff = rb * 128 + (cb ^ ((rb & 7) << 4));
                bf16x8 b0v = *reinterpret_cast<const bf16x8*>(BsB + boff);
                bf16x8 b1v = *reinterpret_cast<const bf16x8*>(BsB + 8192 + boff);
                bf16x8 b2v = *reinterpret_cast<const bf16x8*>(BsB + 16384 + boff);
                acc0[nt] = __builtin_amdgcn_mfma_f32_16x16x32_bf16(a, b0v, acc0[nt], 0, 0, 0);
                acc1[nt] = __builtin_amdgcn_mfma_f32_16x16x32_bf16(a, b1v, acc1[nt], 0, 0, 0);
                acc2[nt] = __builtin_amdgcn_mfma_f32_16x16x32_bf16(a, b2v, acc2[nt], 0, 0, 0);
            }
        }
    }

#pragma unroll
    for (int nt = 0; nt < 4; ++nt) {
        const int col = n0 + 16 * nt + l15;
        const float bq = bq_[col], bk = bk_[col], bc = bc_[col];
#pragma unroll
        for (int r = 0; r < 4; ++r) {
            const int row = m0 + 16 * w + 4 * lq + r;
            const size_t o = (size_t)row * 1024 + col;
            const float qv = acc0[nt][r] + bq;
            qb[o] = f2bf(qv);
            q2b[o] = f2bf((qv < 0.f ? qv : 0.02f * qv) * 0.125f);
            kb[o] = f2bf(acc1[nt][r] + bk);
            k2q[o] = f2bf(sigmoidf_((acc2[nt][r] + bc) * 6.25e-4f));
        }
    }
}

// ---------------------------------------------------------------------------
// scan_ds0: inline gate scan + dS0 outer product. grid (8, 32), 256 threads.
// ---------------------------------------------------------------------------
__global__ __launch_bounds__(256) void scan_ds0(const float* __restrict__ x,
                                                const ushort_t* __restrict__ Kb,
                                                const float* __restrict__ gw_w,
                                                const float* __restrict__ gw_b,
                                                const float* __restrict__ sw_w,
                                                const float* __restrict__ sw_b,
                                                float* __restrict__ gc_out,
                                                float* __restrict__ ab_out,
                                                float* __restrict__ dS0) {
    const int j = blockIdx.x, bh = blockIdx.y;
    const int b = bh >> 4, h = bh & 15;
    const int tid = threadIdx.x;
    const int w = tid >> 6, lane = tid & 63;
    const int l15 = lane & 15, lq = lane >> 4;

    __shared__ float gwl[64], swl[64];
    __shared__ float ctot[8];
    __shared__ float abl[64];
    __shared__ ushort_t KT[64][72];
    __shared__ ushort_t VT[64][72];

    const size_t base = (size_t)(b * 512) * 1024 + h * 64;

    if (tid < 64) gwl[tid] = gw_w[tid];
    else if (tid < 128) swl[tid - 64] = sw_w[tid - 64];
    __syncthreads();
    const float gwb = gw_b[0], swb = sw_b[0];

    const int T = (j + 1) * 64;
    float ps_own = 0.f, dk_own = 0.f;
    for (int i = 0; i * 256 < T; ++i) {
        const int t = i * 256 + tid;
        const int cseg = i * 4 + w;
        if (cseg <= j) {
            const float* xr = x + base + (size_t)t * 1024;
            float dg = 0.f;
#pragma unroll
            for (int d = 0; d < 64; d += 4) {
                float4 xv = *reinterpret_cast<const float4*>(xr + d);
                dg += xv.x * gwl[d] + xv.y * gwl[d + 1] + xv.z * gwl[d + 2] + xv.w * gwl[d + 3];
            }
            float dk = 0.f;
            if (cseg == j) {
                const ushort_t* kr = Kb + base + (size_t)t * 1024;
#pragma unroll
                for (int d = 0; d < 64; d += 8) {
                    union { uint4 v; ushort_t u[8]; } kv;
                    kv.v = *reinterpret_cast<const uint4*>(kr + d);
#pragma unroll
                    for (int q = 0; q < 8; ++q) dk += bf2f(kv.u[q]) * swl[d + q];
                }
            }
            const float g = sigmoidf_(dg + gwb);
            float ps = logf(fmaxf(g, 1e-6f));
#pragma unroll
            for (int off = 1; off < 64; off <<= 1) {
                float v = __shfl_up(ps, off, 64);
                if (lane >= off) ps += v;
            }
            if (lane == 63) ctot[cseg] = ps;
            if (cseg == j) { ps_own = ps; dk_own = dk; }
        }
    }
    __syncthreads();
    if (w == (j & 3)) {
        float coff = 0.f;
        for (int cc = 0; cc < j; ++cc) coff += ctot[cc];
        const float lsum = coff + ps_own;
        const float Gc = expf(fminf(fmaxf(lsum, -30.f), 30.f)) + 1e-6f;
        const float z = dk_own + swb;
        const float a = z * sigmoidf_(z) / Gc;
        abl[lane] = a;
        gc_out[bh * 512 + j * 64 + lane] = Gc;
        ab_out[bh * 512 + j * 64 + lane] = a;
    }
    __syncthreads();

#pragma unroll
    for (int it = 0; it < 4; ++it) {
        const int idx = tid + it * 256;
        const int rr = idx >> 4;
        const int c4 = (idx & 15) << 2;
        const int tau = j * 64 + rr;
        ushort4 kv = *reinterpret_cast<const ushort4*>(Kb + base + (size_t)tau * 1024 + c4);
        float4 xv = *reinterpret_cast<const float4*>(x + base + (size_t)tau * 1024 + c4);
        const float a = abl[rr];
        KT[c4 + 0][rr] = kv.x; KT[c4 + 1][rr] = kv.y;
        KT[c4 + 2][rr] = kv.z; KT[c4 + 3][rr] = kv.w;
        VT[c4 + 0][rr] = f2bf(a * xv.x); VT[c4 + 1][rr] = f2bf(a * xv.y);
        VT[c4 + 2][rr] = f2bf(a * xv.z); VT[c4 + 3][rr] = f2bf(a * xv.w);
    }
    __syncthreads();

    f32x4 st[4];
#pragma unroll
    for (int n = 0; n < 4; ++n) st[n] = (f32x4){0.f, 0.f, 0.f, 0.f};
#pragma unroll
    for (int kk = 0; kk < 64; kk += 32) {
        bf16x8 ak = *reinterpret_cast<const bf16x8*>(&KT[16 * w + l15][kk + 8 * lq]);
#pragma unroll
        for (int n = 0; n < 4; ++n) {
            bf16x8 vb = *reinterpret_cast<const bf16x8*>(&VT[16 * n + l15][kk + 8 * lq]);
            st[n] = __builtin_amdgcn_mfma_f32_16x16x32_bf16(ak, vb, st[n], 0, 0, 0);
        }
    }
    float* o = dS0 + (size_t)(bh * 8 + j) * 4096;
#pragma unroll
    for (int n = 0; n < 4; ++n)
#pragma unroll
        for (int r = 0; r < 4; ++r)
            o[(16 * w + 4 * lq + r) * 64 + 16 * n + l15] = st[n][r];
}

// ---------------------------------------------------------------------------
// out0_ds1: GLA output chunk (inline dS0-prefix) + dS1 + EbT emission.
// Qs/Ks staged via gl16+swizzle. grid (8, 32), 256 threads.
// ---------------------------------------------------------------------------
__global__ __launch_bounds__(256) void out0_ds1(const float* __restrict__ x,
                                                const ushort_t* __restrict__ Qb,
                                                const ushort_t* __restrict__ Kb,
                                                const ushort_t* __restrict__ K2b,
                                                const float* __restrict__ gc,
                                                const float* __restrict__ ab,
                                                const float* __restrict__ dS0,
                                                float* __restrict__ O1out,
                                                float* __restrict__ dS1,
                                                ushort_t* __restrict__ EbT) {
    const int rt = blockIdx.x, bh = blockIdx.y;
    const int b = bh >> 4, h = bh & 15;
    const int c0 = rt * 64;
    const int tid = threadIdx.x;
    const int w = tid >> 6, lane = tid & 63;
    const int l15 = lane & 15, lq = lane >> 4;

    __shared__ __align__(16) char Qs[8192];
    __shared__ __align__(16) char Ks[8192];
    __shared__ ushort_t VT[64][72];
    __shared__ ushort_t K2T[64][72];
    __shared__ ushort_t ET[64][72];
    __shared__ ushort_t Ps[64][72];
    __shared__ ushort_t SBt[64][72];
    __shared__ float av[64], gcv[64];

    const size_t base = (size_t)(b * 512) * 1024 + h * 64;
    const size_t rowB = (size_t)(b * 512 + c0) * 2048 + h * 128;  // byte base of tile row 0

    // gl16 stage Q, K (linear LDS dest, pre-swizzled global src)
#pragma unroll
    for (int is = 0; is < 2; ++is) {
        const int p = tid * 16 + is * 4096;
        const int row = p >> 7;
        const int scb = (p & 127) ^ ((row & 7) << 4);
        gl16((const char*)Qb + rowB + (size_t)row * 2048 + scb, Qs + is * 4096 + w * 1024);
        gl16((const char*)Kb + rowB + (size_t)row * 2048 + scb, Ks + is * 4096 + w * 1024);
    }
    // transposed stages: V^T (=x^T), K2^T
#pragma unroll
    for (int it = 0; it < 4; ++it) {
        const int idx = tid + it * 256;
        const int rr = idx >> 4;
        const int c4 = (idx & 15) << 2;
        const int tau = c0 + rr;
        float4 xv = *reinterpret_cast<const float4*>(x + base + (size_t)tau * 1024 + c4);
        VT[c4 + 0][rr] = f2bf(xv.x); VT[c4 + 1][rr] = f2bf(xv.y);
        VT[c4 + 2][rr] = f2bf(xv.z); VT[c4 + 3][rr] = f2bf(xv.w);
        ushort4 cv = *reinterpret_cast<const ushort4*>(K2b + base + (size_t)tau * 1024 + c4);
        K2T[c4 + 0][rr] = cv.x; K2T[c4 + 1][rr] = cv.y;
        K2T[c4 + 2][rr] = cv.z; K2T[c4 + 3][rr] = cv.w;
    }
    if (tid < 64) av[tid] = ab[bh * 512 + c0 + tid];
    else if (tid < 128) gcv[tid - 64] = gc[bh * 512 + c0 + tid - 64];

    // inline prefix of dS0 chunks < rt -> SBt
#pragma unroll
    for (int ii = 0; ii < 4; ++ii) {
        const int flat = tid * 16 + ii * 4;
        float4 s = {0.f, 0.f, 0.f, 0.f};
        for (int jj = 0; jj < rt; ++jj) {
            float4 v = *reinterpret_cast<const float4*>(dS0 + (size_t)(bh * 8 + jj) * 4096 + flat);
            s.x += v.x; s.y += v.y; s.z += v.z; s.w += v.w;
        }
        const int d = flat >> 6, e = flat & 63;
        SBt[e + 0][d] = f2bf(s.x); SBt[e + 1][d] = f2bf(s.y);
        SBt[e + 2][d] = f2bf(s.z); SBt[e + 3][d] = f2bf(s.w);
    }
    __syncthreads();

    // scores
    const int ra = 16 * w + l15;
    f32x4 sc[4];
#pragma unroll
    for (int n = 0; n < 4; ++n) sc[n] = (f32x4){0.f, 0.f, 0.f, 0.f};
#pragma unroll
    for (int kk = 0; kk < 64; kk += 32) {
        const int cb = (kk + 8 * lq) * 2;
        bf16x8 aq = *reinterpret_cast<const bf16x8*>(Qs + ra * 128 + (cb ^ ((ra & 7) << 4)));
#pragma unroll
        for (int n = 0; n < 4; ++n) {
            const int rb = 16 * n + l15;
            bf16x8 bb = *reinterpret_cast<const bf16x8*>(Ks + rb * 128 + (cb ^ ((rb & 7) << 4)));
            sc[n] = __builtin_amdgcn_mfma_f32_16x16x32_bf16(aq, bb, sc[n], 0, 0, 0);
        }
    }
#pragma unroll
    for (int n = 0; n < 4; ++n) {
        const int cl = 16 * n + l15;
#pragma unroll
        for (int r = 0; r < 4; ++r) {
            const int tl = 16 * w + 4 * lq + r;
            Ps[tl][cl] = f2bf(cl <= tl ? sc[n][r] * av[cl] : 0.f);
        }
    }
    __syncthreads();

    // out: oc = Q @ S + P @ V
    f32x4 oc[4];
#pragma unroll
    for (int n = 0; n < 4; ++n) oc[n] = (f32x4){0.f, 0.f, 0.f, 0.f};
#pragma unroll
    for (int kk = 0; kk < 64; kk += 32) {
        const int cb = (kk + 8 * lq) * 2;
        bf16x8 aq = *reinterpret_cast<const bf16x8*>(Qs + ra * 128 + (cb ^ ((ra & 7) << 4)));
        bf16x8 ap = *reinterpret_cast<const bf16x8*>(&Ps[16 * w + l15][kk + 8 * lq]);
#pragma unroll
        for (int n = 0; n < 4; ++n) {
            bf16x8 sb = *reinterpret_cast<const bf16x8*>(&SBt[16 * n + l15][kk + 8 * lq]);
            oc[n] = __builtin_amdgcn_mfma_f32_16x16x32_bf16(aq, sb, oc[n], 0, 0, 0);
            bf16x8 vb = *reinterpret_cast<const bf16x8*>(&VT[16 * n + l15][kk + 8 * lq]);
            oc[n] = __builtin_amdgcn_mfma_f32_16x16x32_bf16(ap, vb, oc[n], 0, 0, 0);
        }
    }

    // write O1 chunk; build E^T in LDS
#pragma unroll
    for (int n = 0; n < 4; ++n) {
        const int e = 16 * n + l15;
#pragma unroll
        for (int r = 0; r < 4; ++r) {
            const int tl = 16 * w + 4 * lq + r;
            const int tau = c0 + tl;
            const float val = gcv[tl] * oc[n][r];
            O1out[base + (size_t)tau * 1024 + e] = val;
            float ev = 0.f;
            if (tau <= 510) ev = x[base + (size_t)(tau + 1) * 1024 + e] - val;
            ET[e][tl] = f2bf(ev);
        }
    }
    __syncthreads();

    // persist E^T (bf16) for out1: EbT[bh][e][tau]
    {
        const int e = tid >> 2;
        const int tq = (tid & 3) * 16;
        uint4 v0 = *reinterpret_cast<const uint4*>(&ET[e][tq]);
        uint4 v1 = *reinterpret_cast<const uint4*>(&ET[e][tq + 8]);
        ushort_t* dst = EbT + (size_t)(bh * 64 + e) * 512 + c0 + tq;
        *reinterpret_cast<uint4*>(dst) = v0;
        *reinterpret_cast<uint4*>(dst + 8) = v1;
    }

    // dS1 = k2^T @ E
    f32x4 st[4];
#pragma unroll
    for (int n = 0; n < 4; ++n) st[n] = (f32x4){0.f, 0.f, 0.f, 0.f};
#pragma unroll
    for (int kk = 0; kk < 64; kk += 32) {
        bf16x8 ak = *reinterpret_cast<const bf16x8*>(&K2T[16 * w + l15][kk + 8 * lq]);
#pragma unroll
        for (int n = 0; n < 4; ++n) {
            bf16x8 eb = *reinterpret_cast<const bf16x8*>(&ET[16 * n + l15][kk + 8 * lq]);
            st[n] = __builtin_amdgcn_mfma_f32_16x16x32_bf16(ak, eb, st[n], 0, 0, 0);
        }
    }
    float* o = dS1 + (size_t)(bh * 8 + rt) * 4096;
#pragma unroll
    for (int n = 0; n < 4; ++n)
#pragma unroll
        for (int r = 0; r < 4; ++r)
            o[(16 * w + 4 * lq + r) * 64 + 16 * n + l15] = st[n][r];
}

// ---------------------------------------------------------------------------
// out1: MA-branch output (inline dS1-prefix) + final y in bf16.
// Q2s/K2s/ET staged via gl16+swizzle from precomputed q2b/k2q/EbT.
// ---------------------------------------------------------------------------
__global__ __launch_bounds__(256) void out1_k(const ushort_t* __restrict__ Q2b,
                                              const ushort_t* __restrict__ K2b,
                                              const ushort_t* __restrict__ EbT,
                                              const float* __restrict__ O1,
                                              const float* __restrict__ dS1,
                                              ushort_t* __restrict__ yout) {
    const int rt = blockIdx.x, bh = blockIdx.y;
    const int b = bh >> 4, h = bh & 15;
    const int c0 = rt * 64;
    const int tid = threadIdx.x;
    const int w = tid >> 6, lane = tid & 63;
    const int l15 = lane & 15, lq = lane >> 4;

    __shared__ __align__(16) char Q2s[8192];
    __shared__ __align__(16) char K2s[8192];
    __shared__ __align__(16) char ETs[8192];
    __shared__ ushort_t Ps[64][72];
    __shared__ ushort_t SBt[64][72];

    const size_t base = (size_t)(b * 512) * 1024 + h * 64;
    const size_t rowB = (size_t)(b * 512 + c0) * 2048 + h * 128;

#pragma unroll
    for (int is = 0; is < 2; ++is) {
        const int p = tid * 16 + is * 4096;
        const int row = p >> 7;
        const int scb = (p & 127) ^ ((row & 7) << 4);
        gl16((const char*)Q2b + rowB + (size_t)row * 2048 + scb, Q2s + is * 4096 + w * 1024);
        gl16((const char*)K2b + rowB + (size_t)row * 2048 + scb, K2s + is * 4096 + w * 1024);
        gl16((const char*)EbT + (size_t)(bh * 64 + row) * 1024 + c0 * 2 + scb,
             ETs + is * 4096 + w * 1024);
    }
#pragma unroll
    for (int ii = 0; ii < 4; ++ii) {
        const int flat = tid * 16 + ii * 4;
        float4 s = {0.f, 0.f, 0.f, 0.f};
        for (int jj = 0; jj < rt; ++jj) {
            float4 v = *reinterpret_cast<const float4*>(dS1 + (size_t)(bh * 8 + jj) * 4096 + flat);
            s.x += v.x; s.y += v.y; s.z += v.z; s.w += v.w;
        }
        const int d = flat >> 6, e = flat & 63;
        SBt[e + 0][d] = f2bf(s.x); SBt[e + 1][d] = f2bf(s.y);
        SBt[e + 2][d] = f2bf(s.z); SBt[e + 3][d] = f2bf(s.w);
    }
    __syncthreads();

    const int ra = 16 * w + l15;
    f32x4 sc[4];
#pragma unroll
    for (int n = 0; n < 4; ++n) sc[n] = (f32x4){0.f, 0.f, 0.f, 0.f};
#pragma unroll
    for (int kk = 0; kk < 64; kk += 32) {
        const int cb = (kk + 8 * lq) * 2;
        bf16x8 aq = *reinterpret_cast<const bf16x8*>(Q2s + ra * 128 + (cb ^ ((ra & 7) << 4)));
#pragma unroll
        for (int n = 0; n < 4; ++n) {
            const int rb = 16 * n + l15;
            bf16x8 bb = *reinterpret_cast<const bf16x8*>(K2s + rb * 128 + (cb ^ ((rb & 7) << 4)));
            sc[n] = __builtin_amdgcn_mfma_f32_16x16x32_bf16(aq, bb, sc[n], 0, 0, 0);
        }
    }
#pragma unroll
    for (int n = 0; n < 4; ++n) {
        const int cl = 16 * n + l15;
#pragma unroll
        for (int r = 0; r < 4; ++r) {
            const int tl = 16 * w + 4 * lq + r;
            Ps[tl][cl] = f2bf(cl <= tl ? sc[n][r] : 0.f);
        }
    }
    __syncthreads();

    f32x4 oc[4];
#pragma unroll
    for (int n = 0; n < 4; ++n) oc[n] = (f32x4){0.f, 0.f, 0.f, 0.f};
#pragma unroll
    for (int kk = 0; kk < 64; kk += 32) {
        const int cb = (kk + 8 * lq) * 2;
        bf16x8 aq = *reinterpret_cast<const bf16x8*>(Q2s + ra * 128 + (cb ^ ((ra & 7) << 4)));
        bf16x8 ap = *reinterpret_cast<const bf16x8*>(&Ps[16 * w + l15][kk + 8 * lq]);
#pragma unroll
        for (int n = 0; n < 4; ++n) {
            const int rb = 16 * n + l15;
            bf16x8 sb = *reinterpret_cast<const bf16x8*>(&SBt[16 * n + l15][kk + 8 * lq]);
            oc[n] = __builtin_amdgcn_mfma_f32_16x16x32_bf16(aq, sb, oc[n], 0, 0, 0);
            bf16x8 eb = *reinterpret_cast<const bf16x8*>(ETs + rb * 128 + (cb ^ ((rb & 7) << 4)));
            oc[n] = __builtin_amdgcn_mfma_f32_16x16x32_bf16(ap, eb, oc[n], 0, 0, 0);
        }
    }

#pragma unroll
    for (int n = 0; n < 4; ++n) {
        const int e = 16 * n + l15;
#pragma unroll
        for (int r = 0; r < 4; ++r) {
            const int tp = c0 + 16 * w + 4 * lq + r;
            if (tp <= 510) {
                yout[(size_t)(b * 512 + tp + 1) * 1024 + h * 64 + e] =
                    f2bf(O1[base + (size_t)(tp + 1) * 1024 + e] + oc[n][r]);
            }
        }
    }
    if (rt == 0 && tid < 64)
        yout[(size_t)(b * 512) * 1024 + h * 64 + tid] = f2bf(O1[base + tid]);
}

// ---------------------------------------------------------------------------
// gemmP: final projection, fp32 out. gl16 + swizzle, 64x64 tile.
// ---------------------------------------------------------------------------
__global__ __launch_bounds__(256) void gemmP(const ushort_t* __restrict__ Ab,
                                             const ushort_t* __restrict__ WT,
                                             const float* __restrict__ bias,
                                             float* __restrict__ Out) {
    const int m0 = blockIdx.y * 64, n0 = blockIdx.x * 64;
    __shared__ __align__(16) char smem[16384];
    char* AsB = smem;
    char* BsB = smem + 8192;

    const int tid = threadIdx.x;
    const int w = tid >> 6, lane = tid & 63;
    const int l15 = lane & 15, lq = lane >> 4;

    f32x4 acc[4];
#pragma unroll
    for (int i = 0; i < 4; ++i) acc[i] = (f32x4){0.f, 0.f, 0.f, 0.f};

    for (int k0 = 0; k0 < 1024; k0 += 64) {
        __syncthreads();
#pragma unroll
        for (int is = 0; is < 2; ++is) {
            const int p = tid * 16 + is * 4096;
            const int row = p >> 7;
            const int scb = (p & 127) ^ ((row & 7) << 4);
            gl16((const char*)Ab + (((size_t)(m0 + row)) << 11) + (k0 << 1) + scb,
                 AsB + is * 4096 + w * 1024);
            gl16((const char*)WT + (((size_t)(n0 + row)) << 11) + (k0 << 1) + scb,
                 BsB + is * 4096 + w * 1024);
        }
        __syncthreads();
#pragma unroll
        for (int kk = 0; kk < 64; kk += 32) {
            const int cb = (kk + 8 * lq) * 2;
            const int ra = 16 * w + l15;
            bf16x8 a = *reinterpret_cast<const bf16x8*>(AsB + ra * 128 + (cb ^ ((ra & 7) << 4)));
#pragma unroll
            for (int nt = 0; nt < 4; ++nt) {
                const int rb = 16 * nt + l15;
                bf16x8 b = *reinterpret_cast<const bf16x8*>(BsB + rb * 128 + (cb ^ ((rb & 7) << 4)));
                acc[nt] = __builtin_amdgcn_mfma_f32_16x16x32_bf16(a, b, acc[nt], 0, 0, 0);
            }
        }
    }
#pragma unroll
    for (int nt = 0; nt < 4; ++nt) {
        const int col = n0 + 16 * nt + l15;
        const float bcol = bias[col];
#pragma unroll
        for (int r = 0; r < 4; ++r) {
            const int row = m0 + 16 * w + 4 * lq + r;
            Out[(size_t)row * 1024 + col] = acc[nt][r] + bcol;
        }
    }
}

// ---------------------------------------------------------------------------
extern "C" void kernel_launch(void* const* d_in, const int* in_sizes, int n_in,
                              void* d_out, int out_size, void* d_ws, size_t ws_size,
                              hipStream_t stream) {
    const float* x   = (const float*)d_in[0];
    const float* q1w = (const float*)d_in[1];
    const float* q1b = (const float*)d_in[2];
    const float* k1w = (const float*)d_in[3];
    const float* k1b = (const float*)d_in[4];
    const float* k2w = (const float*)d_in[5];
    const float* k2b = (const float*)d_in[6];
    const float* gww = (const float*)d_in[7];
    const float* gwb = (const float*)d_in[8];
    const float* sww = (const float*)d_in[9];
    const float* swb = (const float*)d_in[10];
    const float* cpw = (const float*)d_in[11];
    const float* cpb = (const float*)d_in[12];
    float* out = (float*)d_out;

    float* ws = (float*)d_ws;
    float* O1   = ws;                       // 1M floats
    float* dS0b = ws + 1048576;             // 1M
    float* dS1b = ws + 2097152;             // 1M
    float* gcb  = ws + 3145728;             // 16K
    float* abb  = ws + 3162112;             // 16K
    ushort_t* ub = (ushort_t*)(ws + 3178496);
    ushort_t* xb   = ub;                    // 1M ushorts each
    ushort_t* qb   = ub + 1048576;
    ushort_t* q2b  = ub + 2097152;
    ushort_t* kb   = ub + 3145728;
    ushort_t* k2q  = ub + 4194304;
    ushort_t* EbT  = ub + 5242880;
    ushort_t* wqT  = ub + 6291456;
    ushort_t* wkT  = ub + 7340032;
    ushort_t* wcT  = ub + 8388608;
    ushort_t* wpT  = ub + 9437184;
    ushort_t* ytb  = ub + 10485760;
    // end: ~35 MB of d_ws

    cvtT<<<1536, 256, 0, stream>>>(x, q1w, k1w, k2w, cpw, xb, wqT, wkT, wcT, wpT);
    gemm3<<<dim3(16, 16), 256, 0, stream>>>(xb, wqT, wkT, wcT, q1b, k1b, k2b,
                                            qb, q2b, kb, k2q);
    scan_ds0<<<dim3(8, 32), 256, 0, stream>>>(x, kb, gww, gwb, sww, swb, gcb, abb, dS0b);
    out0_ds1<<<dim3(8, 32), 256, 0, stream>>>(x, qb, kb, k2q, gcb, abb, dS0b, O1, dS1b, EbT);
    out1_k<<<dim3(8, 32), 256, 0, stream>>>(q2b, k2q, EbT, O1, dS1b, ytb);
    gemmP<<<dim3(16, 16), 256, 0, stream>>>(ytb, wpT, cpb, out);
}

// Round 9
// 73.181 us; speedup vs baseline: 4.0671x; 1.1430x over previous
//
#include <hip/hip_runtime.h>
#include <hip/hip_bf16.h>
#include <math.h>

// Problem constants: B=2, L=512, D=1024, H=16, DH=64. N = B*L = 1024.
// 5 dispatches: cvtT -> gemmQKC(+gate-scan+dS0 in z=1 epilogue) -> out0_ds1
//               -> out1_k -> gemmP.

typedef unsigned short ushort_t;
typedef __attribute__((ext_vector_type(8))) short bf16x8;
typedef __attribute__((ext_vector_type(4))) float f32x4;

__device__ __forceinline__ float sigmoidf_(float z) { return 1.f / (1.f + expf(-z)); }

__device__ __forceinline__ ushort_t f2bf(float f) {
    __hip_bfloat16 h = __float2bfloat16(f);
    return *reinterpret_cast<ushort_t*>(&h);
}

__device__ __forceinline__ float bf2f(ushort_t u) {
    union { unsigned int i; float f; } v;
    v.i = ((unsigned int)u) << 16;
    return v.f;
}

__device__ __forceinline__ void gl16(const void* g, void* l) {
    __builtin_amdgcn_global_load_lds(
        (const __attribute__((address_space(1))) unsigned int*)g,
        (__attribute__((address_space(3))) unsigned int*)l, 16, 0, 0);
}

// ---------------------------------------------------------------------------
// cvtT: blocks 0..1023: transpose-convert 4 weights fp32[K][N] -> bf16[N][K].
//       blocks 1024..1535: convert x fp32 -> bf16.
// ---------------------------------------------------------------------------
__global__ __launch_bounds__(256) void cvtT(const float* __restrict__ xs,
                                            const float* __restrict__ w0, const float* __restrict__ w1,
                                            const float* __restrict__ w2, const float* __restrict__ w3,
                                            ushort_t* __restrict__ xd,
                                            ushort_t* __restrict__ t0, ushort_t* __restrict__ t1,
                                            ushort_t* __restrict__ t2, ushort_t* __restrict__ t3) {
    const int blk = blockIdx.x;
    const int tid = threadIdx.x;
    if (blk >= 1024) {
        const int off = ((blk - 1024) * 256 + tid) * 8;
        float4 a = *reinterpret_cast<const float4*>(xs + off);
        float4 b = *reinterpret_cast<const float4*>(xs + off + 4);
        union { uint4 v; ushort_t u[8]; } pk;
        pk.u[0] = f2bf(a.x); pk.u[1] = f2bf(a.y); pk.u[2] = f2bf(a.z); pk.u[3] = f2bf(a.w);
        pk.u[4] = f2bf(b.x); pk.u[5] = f2bf(b.y); pk.u[6] = f2bf(b.z); pk.u[7] = f2bf(b.w);
        *reinterpret_cast<uint4*>(xd + off) = pk.v;
        return;
    }
    const int wi = blk >> 8;
    const float* W = wi == 0 ? w0 : wi == 1 ? w1 : wi == 2 ? w2 : w3;
    ushort_t* WT = wi == 0 ? t0 : wi == 1 ? t1 : wi == 2 ? t2 : t3;
    const int tile = blk & 255;
    const int k0 = (tile >> 4) * 64, n0 = (tile & 15) * 64;
    __shared__ ushort_t T[64][72];
#pragma unroll
    for (int it = 0; it < 4; ++it) {
        const int idx = tid + it * 256;
        const int r = idx >> 4;
        const int c4 = (idx & 15) * 4;
        float4 v = *reinterpret_cast<const float4*>(W + (size_t)(k0 + r) * 1024 + n0 + c4);
        T[r][c4 + 0] = f2bf(v.x); T[r][c4 + 1] = f2bf(v.y);
        T[r][c4 + 2] = f2bf(v.z); T[r][c4 + 3] = f2bf(v.w);
    }
    __syncthreads();
    const int n = tid >> 2;
    const int kq = (tid & 3) * 16;
    union { uint4 v[2]; ushort_t u[16]; } pk;
#pragma unroll
    for (int j = 0; j < 16; ++j) pk.u[j] = T[kq + j][n];
    *reinterpret_cast<uint4*>(WT + (size_t)(n0 + n) * 1024 + k0 + kq) = pk.v[0];
    *reinterpret_cast<uint4*>(WT + (size_t)(n0 + n) * 1024 + k0 + kq + 8) = pk.v[1];
}

// ---------------------------------------------------------------------------
// gemmQKC: z-split GEMM (768 blocks, 3/CU). z=0: Q (qb + leaky q2b). z=1: K
// (kb) + gate-scan + dS0 epilogue (K-tile already in registers). z=2: K2.
// ---------------------------------------------------------------------------
__global__ __launch_bounds__(256) void gemmQKC(const ushort_t* __restrict__ Ab,
                                               const ushort_t* __restrict__ WqT,
                                               const ushort_t* __restrict__ WkT,
                                               const ushort_t* __restrict__ WcT,
                                               const float* __restrict__ bq_,
                                               const float* __restrict__ bk_,
                                               const float* __restrict__ bc_,
                                               const float* __restrict__ x,
                                               const float* __restrict__ gww,
                                               const float* __restrict__ gwb,
                                               const float* __restrict__ sww,
                                               const float* __restrict__ swb,
                                               ushort_t* __restrict__ qb,
                                               ushort_t* __restrict__ q2b,
                                               ushort_t* __restrict__ kb,
                                               ushort_t* __restrict__ k2q,
                                               float* __restrict__ gc_out,
                                               float* __restrict__ ab_out,
                                               float* __restrict__ dS0) {
    const int sel = blockIdx.z;
    const ushort_t* WT = sel == 0 ? WqT : sel == 1 ? WkT : WcT;
    const float* bias = sel == 0 ? bq_ : sel == 1 ? bk_ : bc_;
    const int m0 = blockIdx.y * 64, n0 = blockIdx.x * 64;

    __shared__ __align__(16) char smem[20480];
    char* AsB = smem;
    char* BsB = smem + 8192;

    const int tid = threadIdx.x;
    const int w = tid >> 6, lane = tid & 63;
    const int l15 = lane & 15, lq = lane >> 4;

    f32x4 acc[4];
#pragma unroll
    for (int i = 0; i < 4; ++i) acc[i] = (f32x4){0.f, 0.f, 0.f, 0.f};

    for (int k0 = 0; k0 < 1024; k0 += 64) {
        __syncthreads();
#pragma unroll
        for (int is = 0; is < 2; ++is) {
            const int p = tid * 16 + is * 4096;
            const int row = p >> 7;
            const int scb = (p & 127) ^ ((row & 7) << 4);
            gl16((const char*)Ab + (((size_t)(m0 + row)) << 11) + (k0 << 1) + scb,
                 AsB + is * 4096 + w * 1024);
            gl16((const char*)WT + (((size_t)(n0 + row)) << 11) + (k0 << 1) + scb,
                 BsB + is * 4096 + w * 1024);
        }
        __syncthreads();
#pragma unroll
        for (int kk = 0; kk < 64; kk += 32) {
            const int cb = (kk + 8 * lq) * 2;
            const int ra = 16 * w + l15;
            bf16x8 a = *reinterpret_cast<const bf16x8*>(AsB + ra * 128 + (cb ^ ((ra & 7) << 4)));
#pragma unroll
            for (int nt = 0; nt < 4; ++nt) {
                const int rb = 16 * nt + l15;
                bf16x8 b = *reinterpret_cast<const bf16x8*>(BsB + rb * 128 + (cb ^ ((rb & 7) << 4)));
                acc[nt] = __builtin_amdgcn_mfma_f32_16x16x32_bf16(a, b, acc[nt], 0, 0, 0);
            }
        }
    }

    // fold bias into acc, write per-z outputs
#pragma unroll
    for (int nt = 0; nt < 4; ++nt) {
        const int col = n0 + 16 * nt + l15;
        const float bcol = bias[col];
#pragma unroll
        for (int r = 0; r < 4; ++r) {
            acc[nt][r] += bcol;
            const int row = m0 + 16 * w + 4 * lq + r;
            const size_t o = (size_t)row * 1024 + col;
            const float v = acc[nt][r];
            if (sel == 0) {
                qb[o] = f2bf(v);
                q2b[o] = f2bf((v < 0.f ? v : 0.02f * v) * 0.125f);
            } else if (sel == 1) {
                kb[o] = f2bf(v);
            } else {
                k2q[o] = f2bf(sigmoidf_(v * 6.25e-4f));
            }
        }
    }

    if (sel != 1) return;

    // ---- z=1 epilogue: gate scan + dS0 (K-tile is `acc`, biased) ----
    typedef ushort_t row72[72];
    row72* KT = (row72*)smem;              //  9216 B  [d][tau]
    row72* VT = (row72*)(smem + 9216);     //  9216 B  [e][tau]
    float* gwl  = (float*)(smem + 18432);  // 64
    float* ctot = (float*)(smem + 18688);  // 8
    float* abl  = (float*)(smem + 18720);  // 64
    float* dkl  = (float*)(smem + 18976);  // 64
    const int b = blockIdx.y >> 3, j = blockIdx.y & 7;
    const int h = blockIdx.x;
    const int bh = b * 16 + h;
    const size_t xbase = (size_t)(b * 512) * 1024 + h * 64;

    __syncthreads();   // GEMM LDS reads done -> overlay safe
    if (tid < 64) gwl[tid] = gww[tid];

    // dk[t] = K[t,:].sww  from registers (fp32)
    {
        const float s0 = sww[l15], s1 = sww[16 + l15], s2 = sww[32 + l15], s3 = sww[48 + l15];
#pragma unroll
        for (int r = 0; r < 4; ++r) {
            float p = acc[0][r] * s0 + acc[1][r] * s1 + acc[2][r] * s2 + acc[3][r] * s3;
            p += __shfl_xor(p, 1, 64);
            p += __shfl_xor(p, 2, 64);
            p += __shfl_xor(p, 4, 64);
            p += __shfl_xor(p, 8, 64);
            if (l15 == 0) dkl[16 * w + 4 * lq + r] = p;
        }
    }
    __syncthreads();

    // redundant gate scan over chunks 0..j (wave covers cseg = i*4+w)
    const float gwbv = gwb[0], swbv = swb[0];
    float ps_own = 0.f;
    for (int i = 0; i * 256 < (j + 1) * 64; ++i) {
        const int t = i * 256 + tid;
        const int cseg = i * 4 + w;
        if (cseg <= j) {
            const float* xr = x + xbase + (size_t)t * 1024;
            float dg = 0.f;
#pragma unroll
            for (int d = 0; d < 64; d += 4) {
                float4 xv = *reinterpret_cast<const float4*>(xr + d);
                dg += xv.x * gwl[d] + xv.y * gwl[d + 1] + xv.z * gwl[d + 2] + xv.w * gwl[d + 3];
            }
            const float g = sigmoidf_(dg + gwbv);
            float ps = logf(fmaxf(g, 1e-6f));
#pragma unroll
            for (int off = 1; off < 64; off <<= 1) {
                float v = __shfl_up(ps, off, 64);
                if (lane >= off) ps += v;
            }
            if (lane == 63) ctot[cseg] = ps;
            if (cseg == j) ps_own = ps;
        }
    }
    __syncthreads();
    if (w == (j & 3)) {
        float coff = 0.f;
        for (int cc = 0; cc < j; ++cc) coff += ctot[cc];
        const float lsum = coff + ps_own;
        const float Gc = expf(fminf(fmaxf(lsum, -30.f), 30.f)) + 1e-6f;
        const float z = dkl[lane] + swbv;
        const float a = z * sigmoidf_(z) / Gc;
        abl[lane] = a;
        gc_out[bh * 512 + j * 64 + lane] = Gc;
        ab_out[bh * 512 + j * 64 + lane] = a;
    }
    __syncthreads();

    // KT from registers; VT = (a*x)^T
#pragma unroll
    for (int nt = 0; nt < 4; ++nt)
#pragma unroll
        for (int r = 0; r < 4; ++r)
            KT[16 * nt + l15][16 * w + 4 * lq + r] = f2bf(acc[nt][r]);
#pragma unroll
    for (int it = 0; it < 4; ++it) {
        const int idx = tid + it * 256;
        const int rr = idx >> 4;
        const int c4 = (idx & 15) << 2;
        float4 xv = *reinterpret_cast<const float4*>(x + xbase + (size_t)(j * 64 + rr) * 1024 + c4);
        const float a = abl[rr];
        VT[c4 + 0][rr] = f2bf(a * xv.x); VT[c4 + 1][rr] = f2bf(a * xv.y);
        VT[c4 + 2][rr] = f2bf(a * xv.z); VT[c4 + 3][rr] = f2bf(a * xv.w);
    }
    __syncthreads();

    f32x4 st[4];
#pragma unroll
    for (int n = 0; n < 4; ++n) st[n] = (f32x4){0.f, 0.f, 0.f, 0.f};
#pragma unroll
    for (int kk = 0; kk < 64; kk += 32) {
        bf16x8 ak = *reinterpret_cast<const bf16x8*>(&KT[16 * w + l15][kk + 8 * lq]);
#pragma unroll
        for (int n = 0; n < 4; ++n) {
            bf16x8 vb = *reinterpret_cast<const bf16x8*>(&VT[16 * n + l15][kk + 8 * lq]);
            st[n] = __builtin_amdgcn_mfma_f32_16x16x32_bf16(ak, vb, st[n], 0, 0, 0);
        }
    }
    float* o = dS0 + (size_t)(bh * 8 + j) * 4096;
#pragma unroll
    for (int n = 0; n < 4; ++n)
#pragma unroll
        for (int r = 0; r < 4; ++r)
            o[(16 * w + 4 * lq + r) * 64 + 16 * n + l15] = st[n][r];
}

// ---------------------------------------------------------------------------
// out0_ds1: GLA output chunk (inline dS0-prefix) + dS1 + EbT emission.
// ---------------------------------------------------------------------------
__global__ __launch_bounds__(256) void out0_ds1(const float* __restrict__ x,
                                                const ushort_t* __restrict__ Qb,
                                                const ushort_t* __restrict__ Kb,
                                                const ushort_t* __restrict__ K2b,
                                                const float* __restrict__ gc,
                                                const float* __restrict__ ab,
                                                const float* __restrict__ dS0,
                                                float* __restrict__ O1out,
                                                float* __restrict__ dS1,
                                                ushort_t* __restrict__ EbT) {
    const int rt = blockIdx.x, bh = blockIdx.y;
    const int b = bh >> 4, h = bh & 15;
    const int c0 = rt * 64;
    const int tid = threadIdx.x;
    const int w = tid >> 6, lane = tid & 63;
    const int l15 = lane & 15, lq = lane >> 4;

    __shared__ __align__(16) char Qs[8192];
    __shared__ __align__(16) char Ks[8192];
    __shared__ ushort_t VT[64][72];
    __shared__ ushort_t K2T[64][72];
    __shared__ ushort_t ET[64][72];
    __shared__ ushort_t Ps[64][72];
    __shared__ ushort_t SBt[64][72];
    __shared__ float av[64], gcv[64];

    const size_t base = (size_t)(b * 512) * 1024 + h * 64;
    const size_t rowB = (size_t)(b * 512 + c0) * 2048 + h * 128;

#pragma unroll
    for (int is = 0; is < 2; ++is) {
        const int p = tid * 16 + is * 4096;
        const int row = p >> 7;
        const int scb = (p & 127) ^ ((row & 7) << 4);
        gl16((const char*)Qb + rowB + (size_t)row * 2048 + scb, Qs + is * 4096 + w * 1024);
        gl16((const char*)Kb + rowB + (size_t)row * 2048 + scb, Ks + is * 4096 + w * 1024);
    }
#pragma unroll
    for (int it = 0; it < 4; ++it) {
        const int idx = tid + it * 256;
        const int rr = idx >> 4;
        const int c4 = (idx & 15) << 2;
        const int tau = c0 + rr;
        float4 xv = *reinterpret_cast<const float4*>(x + base + (size_t)tau * 1024 + c4);
        VT[c4 + 0][rr] = f2bf(xv.x); VT[c4 + 1][rr] = f2bf(xv.y);
        VT[c4 + 2][rr] = f2bf(xv.z); VT[c4 + 3][rr] = f2bf(xv.w);
        ushort4 cv = *reinterpret_cast<const ushort4*>(K2b + base + (size_t)tau * 1024 + c4);
        K2T[c4 + 0][rr] = cv.x; K2T[c4 + 1][rr] = cv.y;
        K2T[c4 + 2][rr] = cv.z; K2T[c4 + 3][rr] = cv.w;
    }
    if (tid < 64) av[tid] = ab[bh * 512 + c0 + tid];
    else if (tid < 128) gcv[tid - 64] = gc[bh * 512 + c0 + tid - 64];

#pragma unroll
    for (int ii = 0; ii < 4; ++ii) {
        const int flat = tid * 16 + ii * 4;
        float4 s = {0.f, 0.f, 0.f, 0.f};
        for (int jj = 0; jj < rt; ++jj) {
            float4 v = *reinterpret_cast<const float4*>(dS0 + (size_t)(bh * 8 + jj) * 4096 + flat);
            s.x += v.x; s.y += v.y; s.z += v.z; s.w += v.w;
        }
        const int d = flat >> 6, e = flat & 63;
        SBt[e + 0][d] = f2bf(s.x); SBt[e + 1][d] = f2bf(s.y);
        SBt[e + 2][d] = f2bf(s.z); SBt[e + 3][d] = f2bf(s.w);
    }
    __syncthreads();

    const int ra = 16 * w + l15;
    f32x4 sc[4];
#pragma unroll
    for (int n = 0; n < 4; ++n) sc[n] = (f32x4){0.f, 0.f, 0.f, 0.f};
#pragma unroll
    for (int kk = 0; kk < 64; kk += 32) {
        const int cb = (kk + 8 * lq) * 2;
        bf16x8 aq = *reinterpret_cast<const bf16x8*>(Qs + ra * 128 + (cb ^ ((ra & 7) << 4)));
#pragma unroll
        for (int n = 0; n < 4; ++n) {
            const int rb = 16 * n + l15;
            bf16x8 bb = *reinterpret_cast<const bf16x8*>(Ks + rb * 128 + (cb ^ ((rb & 7) << 4)));
            sc[n] = __builtin_amdgcn_mfma_f32_16x16x32_bf16(aq, bb, sc[n], 0, 0, 0);
        }
    }
#pragma unroll
    for (int n = 0; n < 4; ++n) {
        const int cl = 16 * n + l15;
#pragma unroll
        for (int r = 0; r < 4; ++r) {
            const int tl = 16 * w + 4 * lq + r;
            Ps[tl][cl] = f2bf(cl <= tl ? sc[n][r] * av[cl] : 0.f);
        }
    }
    __syncthreads();

    f32x4 oc[4];
#pragma unroll
    for (int n = 0; n < 4; ++n) oc[n] = (f32x4){0.f, 0.f, 0.f, 0.f};
#pragma unroll
    for (int kk = 0; kk < 64; kk += 32) {
        const int cb = (kk + 8 * lq) * 2;
        bf16x8 aq = *reinterpret_cast<const bf16x8*>(Qs + ra * 128 + (cb ^ ((ra & 7) << 4)));
        bf16x8 ap = *reinterpret_cast<const bf16x8*>(&Ps[16 * w + l15][kk + 8 * lq]);
#pragma unroll
        for (int n = 0; n < 4; ++n) {
            bf16x8 sb = *reinterpret_cast<const bf16x8*>(&SBt[16 * n + l15][kk + 8 * lq]);
            oc[n] = __builtin_amdgcn_mfma_f32_16x16x32_bf16(aq, sb, oc[n], 0, 0, 0);
            bf16x8 vb = *reinterpret_cast<const bf16x8*>(&VT[16 * n + l15][kk + 8 * lq]);
            oc[n] = __builtin_amdgcn_mfma_f32_16x16x32_bf16(ap, vb, oc[n], 0, 0, 0);
        }
    }

#pragma unroll
    for (int n = 0; n < 4; ++n) {
        const int e = 16 * n + l15;
#pragma unroll
        for (int r = 0; r < 4; ++r) {
            const int tl = 16 * w + 4 * lq + r;
            const int tau = c0 + tl;
            const float val = gcv[tl] * oc[n][r];
            O1out[base + (size_t)tau * 1024 + e] = val;
            float ev = 0.f;
            if (tau <= 510) ev = x[base + (size_t)(tau + 1) * 1024 + e] - val;
            ET[e][tl] = f2bf(ev);
        }
    }
    __syncthreads();

    {
        const int e = tid >> 2;
        const int tq = (tid & 3) * 16;
        uint4 v0 = *reinterpret_cast<const uint4*>(&ET[e][tq]);
        uint4 v1 = *reinterpret_cast<const uint4*>(&ET[e][tq + 8]);
        ushort_t* dst = EbT + (size_t)(bh * 64 + e) * 512 + c0 + tq;
        *reinterpret_cast<uint4*>(dst) = v0;
        *reinterpret_cast<uint4*>(dst + 8) = v1;
    }

    f32x4 st[4];
#pragma unroll
    for (int n = 0; n < 4; ++n) st[n] = (f32x4){0.f, 0.f, 0.f, 0.f};
#pragma unroll
    for (int kk = 0; kk < 64; kk += 32) {
        bf16x8 ak = *reinterpret_cast<const bf16x8*>(&K2T[16 * w + l15][kk + 8 * lq]);
#pragma unroll
        for (int n = 0; n < 4; ++n) {
            bf16x8 eb = *reinterpret_cast<const bf16x8*>(&ET[16 * n + l15][kk + 8 * lq]);
            st[n] = __builtin_amdgcn_mfma_f32_16x16x32_bf16(ak, eb, st[n], 0, 0, 0);
        }
    }
    float* o = dS1 + (size_t)(bh * 8 + rt) * 4096;
#pragma unroll
    for (int n = 0; n < 4; ++n)
#pragma unroll
        for (int r = 0; r < 4; ++r)
            o[(16 * w + 4 * lq + r) * 64 + 16 * n + l15] = st[n][r];
}

// ---------------------------------------------------------------------------
// out1: MA-branch output (inline dS1-prefix) + final y in bf16.
// ---------------------------------------------------------------------------
__global__ __launch_bounds__(256) void out1_k(const ushort_t* __restrict__ Q2b,
                                              const ushort_t* __restrict__ K2b,
                                              const ushort_t* __restrict__ EbT,
                                              const float* __restrict__ O1,
                                              const float* __restrict__ dS1,
                                              ushort_t* __restrict__ yout) {
    const int rt = blockIdx.x, bh = blockIdx.y;
    const int b = bh >> 4, h = bh & 15;
    const int c0 = rt * 64;
    const int tid = threadIdx.x;
    const int w = tid >> 6, lane = tid & 63;
    const int l15 = lane & 15, lq = lane >> 4;

    __shared__ __align__(16) char Q2s[8192];
    __shared__ __align__(16) char K2s[8192];
    __shared__ __align__(16) char ETs[8192];
    __shared__ ushort_t Ps[64][72];
    __shared__ ushort_t SBt[64][72];

    const size_t base = (size_t)(b * 512) * 1024 + h * 64;
    const size_t rowB = (size_t)(b * 512 + c0) * 2048 + h * 128;

#pragma unroll
    for (int is = 0; is < 2; ++is) {
        const int p = tid * 16 + is * 4096;
        const int row = p >> 7;
        const int scb = (p & 127) ^ ((row & 7) << 4);
        gl16((const char*)Q2b + rowB + (size_t)row * 2048 + scb, Q2s + is * 4096 + w * 1024);
        gl16((const char*)K2b + rowB + (size_t)row * 2048 + scb, K2s + is * 4096 + w * 1024);
        gl16((const char*)EbT + (size_t)(bh * 64 + row) * 1024 + c0 * 2 + scb,
             ETs + is * 4096 + w * 1024);
    }
#pragma unroll
    for (int ii = 0; ii < 4; ++ii) {
        const int flat = tid * 16 + ii * 4;
        float4 s = {0.f, 0.f, 0.f, 0.f};
        for (int jj = 0; jj < rt; ++jj) {
            float4 v = *reinterpret_cast<const float4*>(dS1 + (size_t)(bh * 8 + jj) * 4096 + flat);
            s.x += v.x; s.y += v.y; s.z += v.z; s.w += v.w;
        }
        const int d = flat >> 6, e = flat & 63;
        SBt[e + 0][d] = f2bf(s.x); SBt[e + 1][d] = f2bf(s.y);
        SBt[e + 2][d] = f2bf(s.z); SBt[e + 3][d] = f2bf(s.w);
    }
    __syncthreads();

    const int ra = 16 * w + l15;
    f32x4 sc[4];
#pragma unroll
    for (int n = 0; n < 4; ++n) sc[n] = (f32x4){0.f, 0.f, 0.f, 0.f};
#pragma unroll
    for (int kk = 0; kk < 64; kk += 32) {
        const int cb = (kk + 8 * lq) * 2;
        bf16x8 aq = *reinterpret_cast<const bf16x8*>(Q2s + ra * 128 + (cb ^ ((ra & 7) << 4)));
#pragma unroll
        for (int n = 0; n < 4; ++n) {
            const int rb = 16 * n + l15;
            bf16x8 bb = *reinterpret_cast<const bf16x8*>(K2s + rb * 128 + (cb ^ ((rb & 7) << 4)));
            sc[n] = __builtin_amdgcn_mfma_f32_16x16x32_bf16(aq, bb, sc[n], 0, 0, 0);
        }
    }
#pragma unroll
    for (int n = 0; n < 4; ++n) {
        const int cl = 16 * n + l15;
#pragma unroll
        for (int r = 0; r < 4; ++r) {
            const int tl = 16 * w + 4 * lq + r;
            Ps[tl][cl] = f2bf(cl <= tl ? sc[n][r] : 0.f);
        }
    }
    __syncthreads();

    f32x4 oc[4];
#pragma unroll
    for (int n = 0; n < 4; ++n) oc[n] = (f32x4){0.f, 0.f, 0.f, 0.f};
#pragma unroll
    for (int kk = 0; kk < 64; kk += 32) {
        const int cb = (kk + 8 * lq) * 2;
        bf16x8 aq = *reinterpret_cast<const bf16x8*>(Q2s + ra * 128 + (cb ^ ((ra & 7) << 4)));
        bf16x8 ap = *reinterpret_cast<const bf16x8*>(&Ps[16 * w + l15][kk + 8 * lq]);
#pragma unroll
        for (int n = 0; n < 4; ++n) {
            const int rb = 16 * n + l15;
            bf16x8 sb = *reinterpret_cast<const bf16x8*>(&SBt[16 * n + l15][kk + 8 * lq]);
            oc[n] = __builtin_amdgcn_mfma_f32_16x16x32_bf16(aq, sb, oc[n], 0, 0, 0);
            bf16x8 eb = *reinterpret_cast<const bf16x8*>(ETs + rb * 128 + (cb ^ ((rb & 7) << 4)));
            oc[n] = __builtin_amdgcn_mfma_f32_16x16x32_bf16(ap, eb, oc[n], 0, 0, 0);
        }
    }

#pragma unroll
    for (int n = 0; n < 4; ++n) {
        const int e = 16 * n + l15;
#pragma unroll
        for (int r = 0; r < 4; ++r) {
            const int tp = c0 + 16 * w + 4 * lq + r;
            if (tp <= 510) {
                yout[(size_t)(b * 512 + tp + 1) * 1024 + h * 64 + e] =
                    f2bf(O1[base + (size_t)(tp + 1) * 1024 + e] + oc[n][r]);
            }
        }
    }
    if (rt == 0 && tid < 64)
        yout[(size_t)(b * 512) * 1024 + h * 64 + tid] = f2bf(O1[base + tid]);
}

// ---------------------------------------------------------------------------
// gemmP: final projection, fp32 out.
// ---------------------------------------------------------------------------
__global__ __launch_bounds__(256) void gemmP(const ushort_t* __restrict__ Ab,
                                             const ushort_t* __restrict__ WT,
                                             const float* __restrict__ bias,
                                             float* __restrict__ Out) {
    const int m0 = blockIdx.y * 64, n0 = blockIdx.x * 64;
    __shared__ __align__(16) char smem[16384];
    char* AsB = smem;
    char* BsB = smem + 8192;

    const int tid = threadIdx.x;
    const int w = tid >> 6, lane = tid & 63;
    const int l15 = lane & 15, lq = lane >> 4;

    f32x4 acc[4];
#pragma unroll
    for (int i = 0; i < 4; ++i) acc[i] = (f32x4){0.f, 0.f, 0.f, 0.f};

    for (int k0 = 0; k0 < 1024; k0 += 64) {
        __syncthreads();
#pragma unroll
        for (int is = 0; is < 2; ++is) {
            const int p = tid * 16 + is * 4096;
            const int row = p >> 7;
            const int scb = (p & 127) ^ ((row & 7) << 4);
            gl16((const char*)Ab + (((size_t)(m0 + row)) << 11) + (k0 << 1) + scb,
                 AsB + is * 4096 + w * 1024);
            gl16((const char*)WT + (((size_t)(n0 + row)) << 11) + (k0 << 1) + scb,
                 BsB + is * 4096 + w * 1024);
        }
        __syncthreads();
#pragma unroll
        for (int kk = 0; kk < 64; kk += 32) {
            const int cb = (kk + 8 * lq) * 2;
            const int ra = 16 * w + l15;
            bf16x8 a = *reinterpret_cast<const bf16x8*>(AsB + ra * 128 + (cb ^ ((ra & 7) << 4)));
#pragma unroll
            for (int nt = 0; nt < 4; ++nt) {
                const int rb = 16 * nt + l15;
                bf16x8 b = *reinterpret_cast<const bf16x8*>(BsB + rb * 128 + (cb ^ ((rb & 7) << 4)));
                acc[nt] = __builtin_amdgcn_mfma_f32_16x16x32_bf16(a, b, acc[nt], 0, 0, 0);
            }
        }
    }
#pragma unroll
    for (int nt = 0; nt < 4; ++nt) {
        const int col = n0 + 16 * nt + l15;
        const float bcol = bias[col];
#pragma unroll
        for (int r = 0; r < 4; ++r) {
            const int row = m0 + 16 * w + 4 * lq + r;
            Out[(size_t)row * 1024 + col] = acc[nt][r] + bcol;
        }
    }
}

// ---------------------------------------------------------------------------
extern "C" void kernel_launch(void* const* d_in, const int* in_sizes, int n_in,
                              void* d_out, int out_size, void* d_ws, size_t ws_size,
                              hipStream_t stream) {
    const float* x   = (const float*)d_in[0];
    const float* q1w = (const float*)d_in[1];
    const float* q1b = (const float*)d_in[2];
    const float* k1w = (const float*)d_in[3];
    const float* k1b = (const float*)d_in[4];
    const float* k2w = (const float*)d_in[5];
    const float* k2b = (const float*)d_in[6];
    const float* gww = (const float*)d_in[7];
    const float* gwb = (const float*)d_in[8];
    const float* sww = (const float*)d_in[9];
    const float* swb = (const float*)d_in[10];
    const float* cpw = (const float*)d_in[11];
    const float* cpb = (const float*)d_in[12];
    float* out = (float*)d_out;

    float* ws = (float*)d_ws;
    float* O1   = ws;                       // 1M floats
    float* dS0b = ws + 1048576;             // 1M
    float* dS1b = ws + 2097152;             // 1M
    float* gcb  = ws + 3145728;             // 16K
    float* abb  = ws + 3162112;             // 16K
    ushort_t* ub = (ushort_t*)(ws + 3178496);
    ushort_t* xb   = ub;                    // 1M ushorts each
    ushort_t* qb   = ub + 1048576;
    ushort_t* q2b  = ub + 2097152;
    ushort_t* kb   = ub + 3145728;
    ushort_t* k2q  = ub + 4194304;
    ushort_t* EbT  = ub + 5242880;
    ushort_t* wqT  = ub + 6291456;
    ushort_t* wkT  = ub + 7340032;
    ushort_t* wcT  = ub + 8388608;
    ushort_t* wpT  = ub + 9437184;
    ushort_t* ytb  = ub + 10485760;
    // end: ~35 MB of d_ws

    cvtT<<<1536, 256, 0, stream>>>(x, q1w, k1w, k2w, cpw, xb, wqT, wkT, wcT, wpT);
    gemmQKC<<<dim3(16, 16, 3), 256, 0, stream>>>(xb, wqT, wkT, wcT, q1b, k1b, k2b,
                                                 x, gww, gwb, sww, swb,
                                                 qb, q2b, kb, k2q, gcb, abb, dS0b);
    out0_ds1<<<dim3(8, 32), 256, 0, stream>>>(x, qb, kb, k2q, gcb, abb, dS0b, O1, dS1b, EbT);
    out1_k<<<dim3(8, 32), 256, 0, stream>>>(q2b, k2q, EbT, O1, dS1b, ytb);
    gemmP<<<dim3(16, 16), 256, 0, stream>>>(ytb, wpT, cpb, out);
}

// Round 10
// 60.861 us; speedup vs baseline: 4.8903x; 1.2024x over previous
//
#include <hip/hip_runtime.h>
#include <hip/hip_bf16.h>
#include <math.h>

// Problem constants: B=2, L=512, D=1024, H=16, DH=64. N = B*L = 1024.
// 5 dispatches: cvtT -> gemmQKC(dbuf, +scan+dS0 in z=1 epilogue) -> out0_ds1(512t)
//               -> out1_k(512t) -> gemmP(512t, dbuf).

typedef unsigned short ushort_t;
typedef __attribute__((ext_vector_type(8))) short bf16x8;
typedef __attribute__((ext_vector_type(4))) float f32x4;

__device__ __forceinline__ float sigmoidf_(float z) { return 1.f / (1.f + expf(-z)); }

__device__ __forceinline__ ushort_t f2bf(float f) {
    __hip_bfloat16 h = __float2bfloat16(f);
    return *reinterpret_cast<ushort_t*>(&h);
}

__device__ __forceinline__ float bf2f(ushort_t u) {
    union { unsigned int i; float f; } v;
    v.i = ((unsigned int)u) << 16;
    return v.f;
}

__device__ __forceinline__ void gl16(const void* g, void* l) {
    __builtin_amdgcn_global_load_lds(
        (const __attribute__((address_space(1))) unsigned int*)g,
        (__attribute__((address_space(3))) unsigned int*)l, 16, 0, 0);
}

// ---------------------------------------------------------------------------
// cvtT: blocks 0..1023: transpose-convert 4 weights fp32[K][N] -> bf16[N][K].
//       blocks 1024..1535: convert x fp32 -> bf16.
// ---------------------------------------------------------------------------
__global__ __launch_bounds__(256) void cvtT(const float* __restrict__ xs,
                                            const float* __restrict__ w0, const float* __restrict__ w1,
                                            const float* __restrict__ w2, const float* __restrict__ w3,
                                            ushort_t* __restrict__ xd,
                                            ushort_t* __restrict__ t0, ushort_t* __restrict__ t1,
                                            ushort_t* __restrict__ t2, ushort_t* __restrict__ t3) {
    const int blk = blockIdx.x;
    const int tid = threadIdx.x;
    if (blk >= 1024) {
        const int off = ((blk - 1024) * 256 + tid) * 8;
        float4 a = *reinterpret_cast<const float4*>(xs + off);
        float4 b = *reinterpret_cast<const float4*>(xs + off + 4);
        union { uint4 v; ushort_t u[8]; } pk;
        pk.u[0] = f2bf(a.x); pk.u[1] = f2bf(a.y); pk.u[2] = f2bf(a.z); pk.u[3] = f2bf(a.w);
        pk.u[4] = f2bf(b.x); pk.u[5] = f2bf(b.y); pk.u[6] = f2bf(b.z); pk.u[7] = f2bf(b.w);
        *reinterpret_cast<uint4*>(xd + off) = pk.v;
        return;
    }
    const int wi = blk >> 8;
    const float* W = wi == 0 ? w0 : wi == 1 ? w1 : wi == 2 ? w2 : w3;
    ushort_t* WT = wi == 0 ? t0 : wi == 1 ? t1 : wi == 2 ? t2 : t3;
    const int tile = blk & 255;
    const int k0 = (tile >> 4) * 64, n0 = (tile & 15) * 64;
    __shared__ ushort_t T[64][72];
#pragma unroll
    for (int it = 0; it < 4; ++it) {
        const int idx = tid + it * 256;
        const int r = idx >> 4;
        const int c4 = (idx & 15) * 4;
        float4 v = *reinterpret_cast<const float4*>(W + (size_t)(k0 + r) * 1024 + n0 + c4);
        T[r][c4 + 0] = f2bf(v.x); T[r][c4 + 1] = f2bf(v.y);
        T[r][c4 + 2] = f2bf(v.z); T[r][c4 + 3] = f2bf(v.w);
    }
    __syncthreads();
    const int n = tid >> 2;
    const int kq = (tid & 3) * 16;
    union { uint4 v[2]; ushort_t u[16]; } pk;
#pragma unroll
    for (int j = 0; j < 16; ++j) pk.u[j] = T[kq + j][n];
    *reinterpret_cast<uint4*>(WT + (size_t)(n0 + n) * 1024 + k0 + kq) = pk.v[0];
    *reinterpret_cast<uint4*>(WT + (size_t)(n0 + n) * 1024 + k0 + kq + 8) = pk.v[1];
}

// ---------------------------------------------------------------------------
// gemmQKC: z-split GEMM (768 blocks), double-buffered stage-early pipeline.
// z=0: Q (qb + leaky q2b). z=1: K (kb) + gate-scan + dS0 epilogue. z=2: K2.
// ---------------------------------------------------------------------------
__global__ __launch_bounds__(256) void gemmQKC(const ushort_t* __restrict__ Ab,
                                               const ushort_t* __restrict__ WqT,
                                               const ushort_t* __restrict__ WkT,
                                               const ushort_t* __restrict__ WcT,
                                               const float* __restrict__ bq_,
                                               const float* __restrict__ bk_,
                                               const float* __restrict__ bc_,
                                               const float* __restrict__ x,
                                               const float* __restrict__ gww,
                                               const float* __restrict__ gwb,
                                               const float* __restrict__ sww,
                                               const float* __restrict__ swb,
                                               ushort_t* __restrict__ qb,
                                               ushort_t* __restrict__ q2b,
                                               ushort_t* __restrict__ kb,
                                               ushort_t* __restrict__ k2q,
                                               float* __restrict__ gc_out,
                                               float* __restrict__ ab_out,
                                               float* __restrict__ dS0) {
    const int sel = blockIdx.z;
    const ushort_t* WT = sel == 0 ? WqT : sel == 1 ? WkT : WcT;
    const float* bias = sel == 0 ? bq_ : sel == 1 ? bk_ : bc_;
    const int m0 = blockIdx.y * 64, n0 = blockIdx.x * 64;

    __shared__ __align__(16) char smem[32768];   // As0,As1,Bs0,Bs1 (8 KB each)

    const int tid = threadIdx.x;
    const int w = tid >> 6, lane = tid & 63;
    const int l15 = lane & 15, lq = lane >> 4;

    f32x4 acc[4];
#pragma unroll
    for (int i = 0; i < 4; ++i) acc[i] = (f32x4){0.f, 0.f, 0.f, 0.f};

    auto stage = [&](int buf, int k0) {
        char* As = smem + buf * 8192;
        char* Bs = smem + 16384 + buf * 8192;
#pragma unroll
        for (int is = 0; is < 2; ++is) {
            const int p = tid * 16 + is * 4096;
            const int row = p >> 7;
            const int scb = (p & 127) ^ ((row & 7) << 4);
            gl16((const char*)Ab + (((size_t)(m0 + row)) << 11) + (k0 << 1) + scb,
                 As + is * 4096 + w * 1024);
            gl16((const char*)WT + (((size_t)(n0 + row)) << 11) + (k0 << 1) + scb,
                 Bs + is * 4096 + w * 1024);
        }
    };

    stage(0, 0);
    __syncthreads();                      // drains vmcnt -> buf0 ready
    for (int k0 = 0; k0 < 1024; k0 += 64) {
        const int cur = (k0 >> 6) & 1;
        if (k0 < 960) stage(cur ^ 1, k0 + 64);   // issue next tile early
        const char* As = smem + cur * 8192;
        const char* Bs = smem + 16384 + cur * 8192;
#pragma unroll
        for (int kk = 0; kk < 64; kk += 32) {
            const int cb = (kk + 8 * lq) * 2;
            const int ra = 16 * w + l15;
            bf16x8 a = *reinterpret_cast<const bf16x8*>(As + ra * 128 + (cb ^ ((ra & 7) << 4)));
#pragma unroll
            for (int nt = 0; nt < 4; ++nt) {
                const int rb = 16 * nt + l15;
                bf16x8 b = *reinterpret_cast<const bf16x8*>(Bs + rb * 128 + (cb ^ ((rb & 7) << 4)));
                acc[nt] = __builtin_amdgcn_mfma_f32_16x16x32_bf16(a, b, acc[nt], 0, 0, 0);
            }
        }
        __syncthreads();                  // next buffer ready; LDS reuse safe
    }

    // fold bias into acc, write per-z outputs
#pragma unroll
    for (int nt = 0; nt < 4; ++nt) {
        const int col = n0 + 16 * nt + l15;
        const float bcol = bias[col];
#pragma unroll
        for (int r = 0; r < 4; ++r) {
            acc[nt][r] += bcol;
            const int row = m0 + 16 * w + 4 * lq + r;
            const size_t o = (size_t)row * 1024 + col;
            const float v = acc[nt][r];
            if (sel == 0) {
                qb[o] = f2bf(v);
                q2b[o] = f2bf((v < 0.f ? v : 0.02f * v) * 0.125f);
            } else if (sel == 1) {
                kb[o] = f2bf(v);
            } else {
                k2q[o] = f2bf(sigmoidf_(v * 6.25e-4f));
            }
        }
    }

    if (sel != 1) return;

    // ---- z=1 epilogue: gate scan + dS0 (K-tile is `acc`, biased) ----
    typedef ushort_t row72[72];
    row72* KT = (row72*)smem;              //  9216 B  [d][tau]
    row72* VT = (row72*)(smem + 9216);     //  9216 B  [e][tau]
    float* gwl  = (float*)(smem + 18432);  // 64
    float* ctot = (float*)(smem + 18688);  // 8
    float* abl  = (float*)(smem + 18720);  // 64
    float* dkl  = (float*)(smem + 18976);  // 64
    const int b = blockIdx.y >> 3, j = blockIdx.y & 7;
    const int h = blockIdx.x;
    const int bh = b * 16 + h;
    const size_t xbase = (size_t)(b * 512) * 1024 + h * 64;

    if (tid < 64) gwl[tid] = gww[tid];

    {
        const float s0 = sww[l15], s1 = sww[16 + l15], s2 = sww[32 + l15], s3 = sww[48 + l15];
#pragma unroll
        for (int r = 0; r < 4; ++r) {
            float p = acc[0][r] * s0 + acc[1][r] * s1 + acc[2][r] * s2 + acc[3][r] * s3;
            p += __shfl_xor(p, 1, 64);
            p += __shfl_xor(p, 2, 64);
            p += __shfl_xor(p, 4, 64);
            p += __shfl_xor(p, 8, 64);
            if (l15 == 0) dkl[16 * w + 4 * lq + r] = p;
        }
    }
    __syncthreads();

    const float gwbv = gwb[0], swbv = swb[0];
    float ps_own = 0.f;
    for (int i = 0; i * 256 < (j + 1) * 64; ++i) {
        const int t = i * 256 + tid;
        const int cseg = i * 4 + w;
        if (cseg <= j) {
            const float* xr = x + xbase + (size_t)t * 1024;
            float dg = 0.f;
#pragma unroll
            for (int d = 0; d < 64; d += 4) {
                float4 xv = *reinterpret_cast<const float4*>(xr + d);
                dg += xv.x * gwl[d] + xv.y * gwl[d + 1] + xv.z * gwl[d + 2] + xv.w * gwl[d + 3];
            }
            const float g = sigmoidf_(dg + gwbv);
            float ps = logf(fmaxf(g, 1e-6f));
#pragma unroll
            for (int off = 1; off < 64; off <<= 1) {
                float v = __shfl_up(ps, off, 64);
                if (lane >= off) ps += v;
            }
            if (lane == 63) ctot[cseg] = ps;
            if (cseg == j) ps_own = ps;
        }
    }
    __syncthreads();
    if (w == (j & 3)) {
        float coff = 0.f;
        for (int cc = 0; cc < j; ++cc) coff += ctot[cc];
        const float lsum = coff + ps_own;
        const float Gc = expf(fminf(fmaxf(lsum, -30.f), 30.f)) + 1e-6f;
        const float z = dkl[lane] + swbv;
        const float a = z * sigmoidf_(z) / Gc;
        abl[lane] = a;
        gc_out[bh * 512 + j * 64 + lane] = Gc;
        ab_out[bh * 512 + j * 64 + lane] = a;
    }
    __syncthreads();

#pragma unroll
    for (int nt = 0; nt < 4; ++nt)
#pragma unroll
        for (int r = 0; r < 4; ++r)
            KT[16 * nt + l15][16 * w + 4 * lq + r] = f2bf(acc[nt][r]);
#pragma unroll
    for (int it = 0; it < 4; ++it) {
        const int idx = tid + it * 256;
        const int rr = idx >> 4;
        const int c4 = (idx & 15) << 2;
        float4 xv = *reinterpret_cast<const float4*>(x + xbase + (size_t)(j * 64 + rr) * 1024 + c4);
        const float a = abl[rr];
        VT[c4 + 0][rr] = f2bf(a * xv.x); VT[c4 + 1][rr] = f2bf(a * xv.y);
        VT[c4 + 2][rr] = f2bf(a * xv.z); VT[c4 + 3][rr] = f2bf(a * xv.w);
    }
    __syncthreads();

    f32x4 st[4];
#pragma unroll
    for (int n = 0; n < 4; ++n) st[n] = (f32x4){0.f, 0.f, 0.f, 0.f};
#pragma unroll
    for (int kk = 0; kk < 64; kk += 32) {
        bf16x8 ak = *reinterpret_cast<const bf16x8*>(&KT[16 * w + l15][kk + 8 * lq]);
#pragma unroll
        for (int n = 0; n < 4; ++n) {
            bf16x8 vb = *reinterpret_cast<const bf16x8*>(&VT[16 * n + l15][kk + 8 * lq]);
            st[n] = __builtin_amdgcn_mfma_f32_16x16x32_bf16(ak, vb, st[n], 0, 0, 0);
        }
    }
    float* o = dS0 + (size_t)(bh * 8 + j) * 4096;
#pragma unroll
    for (int n = 0; n < 4; ++n)
#pragma unroll
        for (int r = 0; r < 4; ++r)
            o[(16 * w + 4 * lq + r) * 64 + 16 * n + l15] = st[n][r];
}

// ---------------------------------------------------------------------------
// out0_ds1 (512 threads, 8 waves): GLA output chunk + dS1 + EbT emission.
// wave = (tw = w>>1 : t/d-tile, eh = w&1 : e/c-half). 2 fragments per wave.
// ---------------------------------------------------------------------------
__global__ __launch_bounds__(512) void out0_ds1(const float* __restrict__ x,
                                                const ushort_t* __restrict__ Qb,
                                                const ushort_t* __restrict__ Kb,
                                                const ushort_t* __restrict__ K2b,
                                                const float* __restrict__ gc,
                                                const float* __restrict__ ab,
                                                const float* __restrict__ dS0,
                                                float* __restrict__ O1out,
                                                float* __restrict__ dS1,
                                                ushort_t* __restrict__ EbT) {
    const int rt = blockIdx.x, bh = blockIdx.y;
    const int b = bh >> 4, h = bh & 15;
    const int c0 = rt * 64;
    const int tid = threadIdx.x;
    const int w = tid >> 6, lane = tid & 63;
    const int l15 = lane & 15, lq = lane >> 4;
    const int tw = w >> 1, eh = w & 1;

    __shared__ __align__(16) char Qs[8192];
    __shared__ __align__(16) char Ks[8192];
    __shared__ ushort_t VT[64][72];
    __shared__ ushort_t K2T[64][72];
    __shared__ ushort_t ET[64][72];
    __shared__ ushort_t Ps[64][72];
    __shared__ ushort_t SBt[64][72];
    __shared__ float av[64], gcv[64];

    const size_t base = (size_t)(b * 512) * 1024 + h * 64;
    const size_t rowB = (size_t)(b * 512 + c0) * 2048 + h * 128;

    {
        const int p = tid * 16;
        const int row = p >> 7;
        const int scb = (p & 127) ^ ((row & 7) << 4);
        gl16((const char*)Qb + rowB + (size_t)row * 2048 + scb, Qs + w * 1024);
        gl16((const char*)Kb + rowB + (size_t)row * 2048 + scb, Ks + w * 1024);
    }
#pragma unroll
    for (int it = 0; it < 2; ++it) {
        const int idx = tid + it * 512;
        const int rr = idx >> 4;
        const int c4 = (idx & 15) << 2;
        const int tau = c0 + rr;
        float4 xv = *reinterpret_cast<const float4*>(x + base + (size_t)tau * 1024 + c4);
        VT[c4 + 0][rr] = f2bf(xv.x); VT[c4 + 1][rr] = f2bf(xv.y);
        VT[c4 + 2][rr] = f2bf(xv.z); VT[c4 + 3][rr] = f2bf(xv.w);
        ushort4 cv = *reinterpret_cast<const ushort4*>(K2b + base + (size_t)tau * 1024 + c4);
        K2T[c4 + 0][rr] = cv.x; K2T[c4 + 1][rr] = cv.y;
        K2T[c4 + 2][rr] = cv.z; K2T[c4 + 3][rr] = cv.w;
    }
    if (tid < 64) av[tid] = ab[bh * 512 + c0 + tid];
    else if (tid < 128) gcv[tid - 64] = gc[bh * 512 + c0 + tid - 64];

#pragma unroll
    for (int ii = 0; ii < 2; ++ii) {
        const int flat = tid * 8 + ii * 4;
        float4 s = {0.f, 0.f, 0.f, 0.f};
        for (int jj = 0; jj < rt; ++jj) {
            float4 v = *reinterpret_cast<const float4*>(dS0 + (size_t)(bh * 8 + jj) * 4096 + flat);
            s.x += v.x; s.y += v.y; s.z += v.z; s.w += v.w;
        }
        const int d = flat >> 6, e = flat & 63;
        SBt[e + 0][d] = f2bf(s.x); SBt[e + 1][d] = f2bf(s.y);
        SBt[e + 2][d] = f2bf(s.z); SBt[e + 3][d] = f2bf(s.w);
    }
    __syncthreads();

    const int ra = 16 * tw + l15;
    f32x4 sc[2];
    sc[0] = (f32x4){0.f, 0.f, 0.f, 0.f};
    sc[1] = (f32x4){0.f, 0.f, 0.f, 0.f};
#pragma unroll
    for (int kk = 0; kk < 64; kk += 32) {
        const int cb = (kk + 8 * lq) * 2;
        bf16x8 aq = *reinterpret_cast<const bf16x8*>(Qs + ra * 128 + (cb ^ ((ra & 7) << 4)));
#pragma unroll
        for (int i = 0; i < 2; ++i) {
            const int rb = 16 * (2 * eh + i) + l15;
            bf16x8 bb = *reinterpret_cast<const bf16x8*>(Ks + rb * 128 + (cb ^ ((rb & 7) << 4)));
            sc[i] = __builtin_amdgcn_mfma_f32_16x16x32_bf16(aq, bb, sc[i], 0, 0, 0);
        }
    }
#pragma unroll
    for (int i = 0; i < 2; ++i) {
        const int cl = 16 * (2 * eh + i) + l15;
#pragma unroll
        for (int r = 0; r < 4; ++r) {
            const int tl = 16 * tw + 4 * lq + r;
            Ps[tl][cl] = f2bf(cl <= tl ? sc[i][r] * av[cl] : 0.f);
        }
    }
    __syncthreads();

    f32x4 oc[2];
    oc[0] = (f32x4){0.f, 0.f, 0.f, 0.f};
    oc[1] = (f32x4){0.f, 0.f, 0.f, 0.f};
#pragma unroll
    for (int kk = 0; kk < 64; kk += 32) {
        const int cb = (kk + 8 * lq) * 2;
        bf16x8 aq = *reinterpret_cast<const bf16x8*>(Qs + ra * 128 + (cb ^ ((ra & 7) << 4)));
        bf16x8 ap = *reinterpret_cast<const bf16x8*>(&Ps[16 * tw + l15][kk + 8 * lq]);
#pragma unroll
        for (int i = 0; i < 2; ++i) {
            const int nb = 16 * (2 * eh + i) + l15;
            bf16x8 sb = *reinterpret_cast<const bf16x8*>(&SBt[nb][kk + 8 * lq]);
            oc[i] = __builtin_amdgcn_mfma_f32_16x16x32_bf16(aq, sb, oc[i], 0, 0, 0);
            bf16x8 vb = *reinterpret_cast<const bf16x8*>(&VT[nb][kk + 8 * lq]);
            oc[i] = __builtin_amdgcn_mfma_f32_16x16x32_bf16(ap, vb, oc[i], 0, 0, 0);
        }
    }

#pragma unroll
    for (int i = 0; i < 2; ++i) {
        const int e = 16 * (2 * eh + i) + l15;
#pragma unroll
        for (int r = 0; r < 4; ++r) {
            const int tl = 16 * tw + 4 * lq + r;
            const int tau = c0 + tl;
            const float val = gcv[tl] * oc[i][r];
            O1out[base + (size_t)tau * 1024 + e] = val;
            float ev = 0.f;
            if (tau <= 510) ev = x[base + (size_t)(tau + 1) * 1024 + e] - val;
            ET[e][tl] = f2bf(ev);
        }
    }
    __syncthreads();

    {
        const int e = tid >> 3;
        const int tq = (tid & 7) * 8;
        uint4 v0 = *reinterpret_cast<const uint4*>(&ET[e][tq]);
        *reinterpret_cast<uint4*>(EbT + (size_t)(bh * 64 + e) * 512 + c0 + tq) = v0;
    }

    f32x4 st[2];
    st[0] = (f32x4){0.f, 0.f, 0.f, 0.f};
    st[1] = (f32x4){0.f, 0.f, 0.f, 0.f};
#pragma unroll
    for (int kk = 0; kk < 64; kk += 32) {
        bf16x8 ak = *reinterpret_cast<const bf16x8*>(&K2T[16 * tw + l15][kk + 8 * lq]);
#pragma unroll
        for (int i = 0; i < 2; ++i) {
            bf16x8 eb = *reinterpret_cast<const bf16x8*>(&ET[16 * (2 * eh + i) + l15][kk + 8 * lq]);
            st[i] = __builtin_amdgcn_mfma_f32_16x16x32_bf16(ak, eb, st[i], 0, 0, 0);
        }
    }
    float* o = dS1 + (size_t)(bh * 8 + rt) * 4096;
#pragma unroll
    for (int i = 0; i < 2; ++i)
#pragma unroll
        for (int r = 0; r < 4; ++r)
            o[(16 * tw + 4 * lq + r) * 64 + 16 * (2 * eh + i) + l15] = st[i][r];
}

// ---------------------------------------------------------------------------
// out1 (512 threads): MA-branch output + final y in bf16.
// ---------------------------------------------------------------------------
__global__ __launch_bounds__(512) void out1_k(const ushort_t* __restrict__ Q2b,
                                              const ushort_t* __restrict__ K2b,
                                              const ushort_t* __restrict__ EbT,
                                              const float* __restrict__ O1,
                                              const float* __restrict__ dS1,
                                              ushort_t* __restrict__ yout) {
    const int rt = blockIdx.x, bh = blockIdx.y;
    const int b = bh >> 4, h = bh & 15;
    const int c0 = rt * 64;
    const int tid = threadIdx.x;
    const int w = tid >> 6, lane = tid & 63;
    const int l15 = lane & 15, lq = lane >> 4;
    const int tw = w >> 1, eh = w & 1;

    __shared__ __align__(16) char Q2s[8192];
    __shared__ __align__(16) char K2s[8192];
    __shared__ __align__(16) char ETs[8192];
    __shared__ ushort_t Ps[64][72];
    __shared__ ushort_t SBt[64][72];

    const size_t base = (size_t)(b * 512) * 1024 + h * 64;
    const size_t rowB = (size_t)(b * 512 + c0) * 2048 + h * 128;

    {
        const int p = tid * 16;
        const int row = p >> 7;
        const int scb = (p & 127) ^ ((row & 7) << 4);
        gl16((const char*)Q2b + rowB + (size_t)row * 2048 + scb, Q2s + w * 1024);
        gl16((const char*)K2b + rowB + (size_t)row * 2048 + scb, K2s + w * 1024);
        gl16((const char*)EbT + (size_t)(bh * 64 + row) * 1024 + c0 * 2 + scb, ETs + w * 1024);
    }
#pragma unroll
    for (int ii = 0; ii < 2; ++ii) {
        const int flat = tid * 8 + ii * 4;
        float4 s = {0.f, 0.f, 0.f, 0.f};
        for (int jj = 0; jj < rt; ++jj) {
            float4 v = *reinterpret_cast<const float4*>(dS1 + (size_t)(bh * 8 + jj) * 4096 + flat);
            s.x += v.x; s.y += v.y; s.z += v.z; s.w += v.w;
        }
        const int d = flat >> 6, e = flat & 63;
        SBt[e + 0][d] = f2bf(s.x); SBt[e + 1][d] = f2bf(s.y);
        SBt[e + 2][d] = f2bf(s.z); SBt[e + 3][d] = f2bf(s.w);
    }
    __syncthreads();

    const int ra = 16 * tw + l15;
    f32x4 sc[2];
    sc[0] = (f32x4){0.f, 0.f, 0.f, 0.f};
    sc[1] = (f32x4){0.f, 0.f, 0.f, 0.f};
#pragma unroll
    for (int kk = 0; kk < 64; kk += 32) {
        const int cb = (kk + 8 * lq) * 2;
        bf16x8 aq = *reinterpret_cast<const bf16x8*>(Q2s + ra * 128 + (cb ^ ((ra & 7) << 4)));
#pragma unroll
        for (int i = 0; i < 2; ++i) {
            const int rb = 16 * (2 * eh + i) + l15;
            bf16x8 bb = *reinterpret_cast<const bf16x8*>(K2s + rb * 128 + (cb ^ ((rb & 7) << 4)));
            sc[i] = __builtin_amdgcn_mfma_f32_16x16x32_bf16(aq, bb, sc[i], 0, 0, 0);
        }
    }
#pragma unroll
    for (int i = 0; i < 2; ++i) {
        const int cl = 16 * (2 * eh + i) + l15;
#pragma unroll
        for (int r = 0; r < 4; ++r) {
            const int tl = 16 * tw + 4 * lq + r;
            Ps[tl][cl] = f2bf(cl <= tl ? sc[i][r] : 0.f);
        }
    }
    __syncthreads();

    f32x4 oc[2];
    oc[0] = (f32x4){0.f, 0.f, 0.f, 0.f};
    oc[1] = (f32x4){0.f, 0.f, 0.f, 0.f};
#pragma unroll
    for (int kk = 0; kk < 64; kk += 32) {
        const int cb = (kk + 8 * lq) * 2;
        bf16x8 aq = *reinterpret_cast<const bf16x8*>(Q2s + ra * 128 + (cb ^ ((ra & 7) << 4)));
        bf16x8 ap = *reinterpret_cast<const bf16x8*>(&Ps[16 * tw + l15][kk + 8 * lq]);
#pragma unroll
        for (int i = 0; i < 2; ++i) {
            const int rb = 16 * (2 * eh + i) + l15;
            bf16x8 sb = *reinterpret_cast<const bf16x8*>(&SBt[rb][kk + 8 * lq]);
            oc[i] = __builtin_amdgcn_mfma_f32_16x16x32_bf16(aq, sb, oc[i], 0, 0, 0);
            bf16x8 eb = *reinterpret_cast<const bf16x8*>(ETs + rb * 128 + (cb ^ ((rb & 7) << 4)));
            oc[i] = __builtin_amdgcn_mfma_f32_16x16x32_bf16(ap, eb, oc[i], 0, 0, 0);
        }
    }

#pragma unroll
    for (int i = 0; i < 2; ++i) {
        const int e = 16 * (2 * eh + i) + l15;
#pragma unroll
        for (int r = 0; r < 4; ++r) {
            const int tp = c0 + 16 * tw + 4 * lq + r;
            if (tp <= 510) {
                yout[(size_t)(b * 512 + tp + 1) * 1024 + h * 64 + e] =
                    f2bf(O1[base + (size_t)(tp + 1) * 1024 + e] + oc[i][r]);
            }
        }
    }
    if (rt == 0 && tid < 64)
        yout[(size_t)(b * 512) * 1024 + h * 64 + tid] = f2bf(O1[base + tid]);
}

// ---------------------------------------------------------------------------
// gemmP (512 threads): final projection, fp32 out, dbuf stage-early.
// wave = (mw = w>>1 : m-tile, nh = w&1 : n-half).
// ---------------------------------------------------------------------------
__global__ __launch_bounds__(512) void gemmP(const ushort_t* __restrict__ Ab,
                                             const ushort_t* __restrict__ WT,
                                             const float* __restrict__ bias,
                                             float* __restrict__ Out) {
    const int m0 = blockIdx.y * 64, n0 = blockIdx.x * 64;
    __shared__ __align__(16) char smem[32768];   // As0,As1,Bs0,Bs1

    const int tid = threadIdx.x;
    const int w = tid >> 6, lane = tid & 63;
    const int l15 = lane & 15, lq = lane >> 4;
    const int mw = w >> 1, nh = w & 1;

    f32x4 acc[2];
    acc[0] = (f32x4){0.f, 0.f, 0.f, 0.f};
    acc[1] = (f32x4){0.f, 0.f, 0.f, 0.f};

    auto stage = [&](int buf, int k0) {
        const int p = tid * 16;
        const int row = p >> 7;
        const int scb = (p & 127) ^ ((row & 7) << 4);
        gl16((const char*)Ab + (((size_t)(m0 + row)) << 11) + (k0 << 1) + scb,
             smem + buf * 8192 + w * 1024);
        gl16((const char*)WT + (((size_t)(n0 + row)) << 11) + (k0 << 1) + scb,
             smem + 16384 + buf * 8192 + w * 1024);
    };

    stage(0, 0);
    __syncthreads();
    for (int k0 = 0; k0 < 1024; k0 += 64) {
        const int cur = (k0 >> 6) & 1;
        if (k0 < 960) stage(cur ^ 1, k0 + 64);
        const char* As = smem + cur * 8192;
        const char* Bs = smem + 16384 + cur * 8192;
#pragma unroll
        for (int kk = 0; kk < 64; kk += 32) {
            const int cb = (kk + 8 * lq) * 2;
            const int ra = 16 * mw + l15;
            bf16x8 a = *reinterpret_cast<const bf16x8*>(As + ra * 128 + (cb ^ ((ra & 7) << 4)));
#pragma unroll
            for (int i = 0; i < 2; ++i) {
                const int rb = 16 * (2 * nh + i) + l15;
                bf16x8 b = *reinterpret_cast<const bf16x8*>(Bs + rb * 128 + (cb ^ ((rb & 7) << 4)));
                acc[i] = __builtin_amdgcn_mfma_f32_16x16x32_bf16(a, b, acc[i], 0, 0, 0);
            }
        }
        __syncthreads();
    }
#pragma unroll
    for (int i = 0; i < 2; ++i) {
        const int col = n0 + 16 * (2 * nh + i) + l15;
        const float bcol = bias[col];
#pragma unroll
        for (int r = 0; r < 4; ++r) {
            const int row = m0 + 16 * mw + 4 * lq + r;
            Out[(size_t)row * 1024 + col] = acc[i][r] + bcol;
        }
    }
}

// ---------------------------------------------------------------------------
extern "C" void kernel_launch(void* const* d_in, const int* in_sizes, int n_in,
                              void* d_out, int out_size, void* d_ws, size_t ws_size,
                              hipStream_t stream) {
    const float* x   = (const float*)d_in[0];
    const float* q1w = (const float*)d_in[1];
    const float* q1b = (const float*)d_in[2];
    const float* k1w = (const float*)d_in[3];
    const float* k1b = (const float*)d_in[4];
    const float* k2w = (const float*)d_in[5];
    const float* k2b = (const float*)d_in[6];
    const float* gww = (const float*)d_in[7];
    const float* gwb = (const float*)d_in[8];
    const float* sww = (const float*)d_in[9];
    const float* swb = (const float*)d_in[10];
    const float* cpw = (const float*)d_in[11];
    const float* cpb = (const float*)d_in[12];
    float* out = (float*)d_out;

    float* ws = (float*)d_ws;
    float* O1   = ws;                       // 1M floats
    float* dS0b = ws + 1048576;             // 1M
    float* dS1b = ws + 2097152;             // 1M
    float* gcb  = ws + 3145728;             // 16K
    float* abb  = ws + 3162112;             // 16K
    ushort_t* ub = (ushort_t*)(ws + 3178496);
    ushort_t* xb   = ub;                    // 1M ushorts each
    ushort_t* qb   = ub + 1048576;
    ushort_t* q2b  = ub + 2097152;
    ushort_t* kb   = ub + 3145728;
    ushort_t* k2q  = ub + 4194304;
    ushort_t* EbT  = ub + 5242880;
    ushort_t* wqT  = ub + 6291456;
    ushort_t* wkT  = ub + 7340032;
    ushort_t* wcT  = ub + 8388608;
    ushort_t* wpT  = ub + 9437184;
    ushort_t* ytb  = ub + 10485760;
    // end: ~35 MB of d_ws

    cvtT<<<1536, 256, 0, stream>>>(x, q1w, k1w, k2w, cpw, xb, wqT, wkT, wcT, wpT);
    gemmQKC<<<dim3(16, 16, 3), 256, 0, stream>>>(xb, wqT, wkT, wcT, q1b, k1b, k2b,
                                                 x, gww, gwb, sww, swb,
                                                 qb, q2b, kb, k2q, gcb, abb, dS0b);
    out0_ds1<<<dim3(8, 32), 512, 0, stream>>>(x, qb, kb, k2q, gcb, abb, dS0b, O1, dS1b, EbT);
    out1_k<<<dim3(8, 32), 512, 0, stream>>>(q2b, k2q, EbT, O1, dS1b, ytb);
    gemmP<<<dim3(16, 16), 512, 0, stream>>>(ytb, wpT, cpb, out);
}

// Round 11
// 57.521 us; speedup vs baseline: 5.1743x; 1.0581x over previous
//
#include <hip/hip_runtime.h>
#include <hip/hip_bf16.h>
#include <math.h>

// Problem constants: B=2, L=512, D=1024, H=16, DH=64. N = B*L = 1024.
// 5 dispatches: cvtT -> gemmQKC(3-deep counted-vmcnt pipeline, +scan+dS0 in
// z=1 epilogue) -> out0_ds1(512t) -> out1_k(512t) -> gemmP(512t, 3-deep).

typedef unsigned short ushort_t;
typedef __attribute__((ext_vector_type(8))) short bf16x8;
typedef __attribute__((ext_vector_type(4))) float f32x4;

__device__ __forceinline__ float sigmoidf_(float z) { return 1.f / (1.f + expf(-z)); }

__device__ __forceinline__ ushort_t f2bf(float f) {
    __hip_bfloat16 h = __float2bfloat16(f);
    return *reinterpret_cast<ushort_t*>(&h);
}

__device__ __forceinline__ float bf2f(ushort_t u) {
    union { unsigned int i; float f; } v;
    v.i = ((unsigned int)u) << 16;
    return v.f;
}

__device__ __forceinline__ void gl16(const void* g, void* l) {
    __builtin_amdgcn_global_load_lds(
        (const __attribute__((address_space(1))) unsigned int*)g,
        (__attribute__((address_space(3))) unsigned int*)l, 16, 0, 0);
}

// ---------------------------------------------------------------------------
// cvtT: blocks 0..1023: transpose-convert 4 weights fp32[K][N] -> bf16[N][K].
//       blocks 1024..1535: convert x fp32 -> bf16.
// ---------------------------------------------------------------------------
__global__ __launch_bounds__(256) void cvtT(const float* __restrict__ xs,
                                            const float* __restrict__ w0, const float* __restrict__ w1,
                                            const float* __restrict__ w2, const float* __restrict__ w3,
                                            ushort_t* __restrict__ xd,
                                            ushort_t* __restrict__ t0, ushort_t* __restrict__ t1,
                                            ushort_t* __restrict__ t2, ushort_t* __restrict__ t3) {
    const int blk = blockIdx.x;
    const int tid = threadIdx.x;
    if (blk >= 1024) {
        const int off = ((blk - 1024) * 256 + tid) * 8;
        float4 a = *reinterpret_cast<const float4*>(xs + off);
        float4 b = *reinterpret_cast<const float4*>(xs + off + 4);
        union { uint4 v; ushort_t u[8]; } pk;
        pk.u[0] = f2bf(a.x); pk.u[1] = f2bf(a.y); pk.u[2] = f2bf(a.z); pk.u[3] = f2bf(a.w);
        pk.u[4] = f2bf(b.x); pk.u[5] = f2bf(b.y); pk.u[6] = f2bf(b.z); pk.u[7] = f2bf(b.w);
        *reinterpret_cast<uint4*>(xd + off) = pk.v;
        return;
    }
    const int wi = blk >> 8;
    const float* W = wi == 0 ? w0 : wi == 1 ? w1 : wi == 2 ? w2 : w3;
    ushort_t* WT = wi == 0 ? t0 : wi == 1 ? t1 : wi == 2 ? t2 : t3;
    const int tile = blk & 255;
    const int k0 = (tile >> 4) * 64, n0 = (tile & 15) * 64;
    __shared__ ushort_t T[64][72];
#pragma unroll
    for (int it = 0; it < 4; ++it) {
        const int idx = tid + it * 256;
        const int r = idx >> 4;
        const int c4 = (idx & 15) * 4;
        float4 v = *reinterpret_cast<const float4*>(W + (size_t)(k0 + r) * 1024 + n0 + c4);
        T[r][c4 + 0] = f2bf(v.x); T[r][c4 + 1] = f2bf(v.y);
        T[r][c4 + 2] = f2bf(v.z); T[r][c4 + 3] = f2bf(v.w);
    }
    __syncthreads();
    const int n = tid >> 2;
    const int kq = (tid & 3) * 16;
    union { uint4 v[2]; ushort_t u[16]; } pk;
#pragma unroll
    for (int j = 0; j < 16; ++j) pk.u[j] = T[kq + j][n];
    *reinterpret_cast<uint4*>(WT + (size_t)(n0 + n) * 1024 + k0 + kq) = pk.v[0];
    *reinterpret_cast<uint4*>(WT + (size_t)(n0 + n) * 1024 + k0 + kq + 8) = pk.v[1];
}

// ---------------------------------------------------------------------------
// gemmQKC: z-split GEMM (768 blocks), 3-deep counted-vmcnt pipeline.
// z=0: Q (qb + leaky q2b). z=1: K (kb) + gate-scan + dS0 epilogue. z=2: K2.
// Per stage: 4 gl16/thread. Steady-state wait vmcnt(8) (2 newer stages).
// ---------------------------------------------------------------------------
__global__ __launch_bounds__(256) void gemmQKC(const ushort_t* __restrict__ Ab,
                                               const ushort_t* __restrict__ WqT,
                                               const ushort_t* __restrict__ WkT,
                                               const ushort_t* __restrict__ WcT,
                                               const float* __restrict__ bq_,
                                               const float* __restrict__ bk_,
                                               const float* __restrict__ bc_,
                                               const float* __restrict__ x,
                                               const float* __restrict__ gww,
                                               const float* __restrict__ gwb,
                                               const float* __restrict__ sww,
                                               const float* __restrict__ swb,
                                               ushort_t* __restrict__ qb,
                                               ushort_t* __restrict__ q2b,
                                               ushort_t* __restrict__ kb,
                                               ushort_t* __restrict__ k2q,
                                               float* __restrict__ gc_out,
                                               float* __restrict__ ab_out,
                                               float* __restrict__ dS0) {
    const int sel = blockIdx.z;
    const ushort_t* WT = sel == 0 ? WqT : sel == 1 ? WkT : WcT;
    const float* bias = sel == 0 ? bq_ : sel == 1 ? bk_ : bc_;
    const int m0 = blockIdx.y * 64, n0 = blockIdx.x * 64;

    __shared__ __align__(16) char smem[49152];   // As[3] @0, Bs[3] @24576 (8 KB each)

    const int tid = threadIdx.x;
    const int w = tid >> 6, lane = tid & 63;
    const int l15 = lane & 15, lq = lane >> 4;

    f32x4 acc[4];
#pragma unroll
    for (int i = 0; i < 4; ++i) acc[i] = (f32x4){0.f, 0.f, 0.f, 0.f};

    auto stage = [&](int buf, int k0) {
        char* As = smem + buf * 8192;
        char* Bs = smem + 24576 + buf * 8192;
#pragma unroll
        for (int is = 0; is < 2; ++is) {
            const int p = tid * 16 + is * 4096;
            const int row = p >> 7;
            const int scb = (p & 127) ^ ((row & 7) << 4);
            gl16((const char*)Ab + (((size_t)(m0 + row)) << 11) + (k0 << 1) + scb,
                 As + is * 4096 + w * 1024);
            gl16((const char*)WT + (((size_t)(n0 + row)) << 11) + (k0 << 1) + scb,
                 Bs + is * 4096 + w * 1024);
        }
    };

    stage(0, 0);
    stage(1, 64);
#pragma unroll
    for (int it = 0; it < 16; ++it) {
        const int k0 = it * 64;
        const int cur = it % 3;
        if (it < 14) stage((it + 2) % 3, k0 + 128);
        if (it < 14)      asm volatile("s_waitcnt vmcnt(8)" ::: "memory");
        else if (it == 14) asm volatile("s_waitcnt vmcnt(4)" ::: "memory");
        else               asm volatile("s_waitcnt vmcnt(0)" ::: "memory");
        __builtin_amdgcn_sched_barrier(0);
        __builtin_amdgcn_s_barrier();
        const char* As = smem + cur * 8192;
        const char* Bs = smem + 24576 + cur * 8192;
#pragma unroll
        for (int kk = 0; kk < 64; kk += 32) {
            const int cb = (kk + 8 * lq) * 2;
            const int ra = 16 * w + l15;
            bf16x8 a = *reinterpret_cast<const bf16x8*>(As + ra * 128 + (cb ^ ((ra & 7) << 4)));
#pragma unroll
            for (int nt = 0; nt < 4; ++nt) {
                const int rb = 16 * nt + l15;
                bf16x8 b = *reinterpret_cast<const bf16x8*>(Bs + rb * 128 + (cb ^ ((rb & 7) << 4)));
                acc[nt] = __builtin_amdgcn_mfma_f32_16x16x32_bf16(a, b, acc[nt], 0, 0, 0);
            }
        }
        asm volatile("s_waitcnt lgkmcnt(0)" ::: "memory");
        __builtin_amdgcn_sched_barrier(0);
        __builtin_amdgcn_s_barrier();
    }

    // fold bias into acc, write per-z outputs
#pragma unroll
    for (int nt = 0; nt < 4; ++nt) {
        const int col = n0 + 16 * nt + l15;
        const float bcol = bias[col];
#pragma unroll
        for (int r = 0; r < 4; ++r) {
            acc[nt][r] += bcol;
            const int row = m0 + 16 * w + 4 * lq + r;
            const size_t o = (size_t)row * 1024 + col;
            const float v = acc[nt][r];
            if (sel == 0) {
                qb[o] = f2bf(v);
                q2b[o] = f2bf((v < 0.f ? v : 0.02f * v) * 0.125f);
            } else if (sel == 1) {
                kb[o] = f2bf(v);
            } else {
                k2q[o] = f2bf(sigmoidf_(v * 6.25e-4f));
            }
        }
    }

    if (sel != 1) return;

    // ---- z=1 epilogue: gate scan + dS0 (K-tile is `acc`, biased) ----
    typedef ushort_t row72[72];
    row72* KT = (row72*)smem;              //  9216 B  [d][tau]
    row72* VT = (row72*)(smem + 9216);     //  9216 B  [e][tau]
    float* gwl  = (float*)(smem + 18432);  // 64
    float* ctot = (float*)(smem + 18688);  // 8
    float* abl  = (float*)(smem + 18720);  // 64
    float* dkl  = (float*)(smem + 18976);  // 64
    const int b = blockIdx.y >> 3, j = blockIdx.y & 7;
    const int h = blockIdx.x;
    const int bh = b * 16 + h;
    const size_t xbase = (size_t)(b * 512) * 1024 + h * 64;

    if (tid < 64) gwl[tid] = gww[tid];

    {
        const float s0 = sww[l15], s1 = sww[16 + l15], s2 = sww[32 + l15], s3 = sww[48 + l15];
#pragma unroll
        for (int r = 0; r < 4; ++r) {
            float p = acc[0][r] * s0 + acc[1][r] * s1 + acc[2][r] * s2 + acc[3][r] * s3;
            p += __shfl_xor(p, 1, 64);
            p += __shfl_xor(p, 2, 64);
            p += __shfl_xor(p, 4, 64);
            p += __shfl_xor(p, 8, 64);
            if (l15 == 0) dkl[16 * w + 4 * lq + r] = p;
        }
    }
    __syncthreads();

    const float gwbv = gwb[0], swbv = swb[0];
    float ps_own = 0.f;
    for (int i = 0; i * 256 < (j + 1) * 64; ++i) {
        const int t = i * 256 + tid;
        const int cseg = i * 4 + w;
        if (cseg <= j) {
            const float* xr = x + xbase + (size_t)t * 1024;
            float dg = 0.f;
#pragma unroll
            for (int d = 0; d < 64; d += 4) {
                float4 xv = *reinterpret_cast<const float4*>(xr + d);
                dg += xv.x * gwl[d] + xv.y * gwl[d + 1] + xv.z * gwl[d + 2] + xv.w * gwl[d + 3];
            }
            const float g = sigmoidf_(dg + gwbv);
            float ps = logf(fmaxf(g, 1e-6f));
#pragma unroll
            for (int off = 1; off < 64; off <<= 1) {
                float v = __shfl_up(ps, off, 64);
                if (lane >= off) ps += v;
            }
            if (lane == 63) ctot[cseg] = ps;
            if (cseg == j) ps_own = ps;
        }
    }
    __syncthreads();
    if (w == (j & 3)) {
        float coff = 0.f;
        for (int cc = 0; cc < j; ++cc) coff += ctot[cc];
        const float lsum = coff + ps_own;
        const float Gc = expf(fminf(fmaxf(lsum, -30.f), 30.f)) + 1e-6f;
        const float z = dkl[lane] + swbv;
        const float a = z * sigmoidf_(z) / Gc;
        abl[lane] = a;
        gc_out[bh * 512 + j * 64 + lane] = Gc;
        ab_out[bh * 512 + j * 64 + lane] = a;
    }
    __syncthreads();

#pragma unroll
    for (int nt = 0; nt < 4; ++nt)
#pragma unroll
        for (int r = 0; r < 4; ++r)
            KT[16 * nt + l15][16 * w + 4 * lq + r] = f2bf(acc[nt][r]);
#pragma unroll
    for (int it = 0; it < 4; ++it) {
        const int idx = tid + it * 256;
        const int rr = idx >> 4;
        const int c4 = (idx & 15) << 2;
        float4 xv = *reinterpret_cast<const float4*>(x + xbase + (size_t)(j * 64 + rr) * 1024 + c4);
        const float a = abl[rr];
        VT[c4 + 0][rr] = f2bf(a * xv.x); VT[c4 + 1][rr] = f2bf(a * xv.y);
        VT[c4 + 2][rr] = f2bf(a * xv.z); VT[c4 + 3][rr] = f2bf(a * xv.w);
    }
    __syncthreads();

    f32x4 st[4];
#pragma unroll
    for (int n = 0; n < 4; ++n) st[n] = (f32x4){0.f, 0.f, 0.f, 0.f};
#pragma unroll
    for (int kk = 0; kk < 64; kk += 32) {
        bf16x8 ak = *reinterpret_cast<const bf16x8*>(&KT[16 * w + l15][kk + 8 * lq]);
#pragma unroll
        for (int n = 0; n < 4; ++n) {
            bf16x8 vb = *reinterpret_cast<const bf16x8*>(&VT[16 * n + l15][kk + 8 * lq]);
            st[n] = __builtin_amdgcn_mfma_f32_16x16x32_bf16(ak, vb, st[n], 0, 0, 0);
        }
    }
    float* o = dS0 + (size_t)(bh * 8 + j) * 4096;
#pragma unroll
    for (int n = 0; n < 4; ++n)
#pragma unroll
        for (int r = 0; r < 4; ++r)
            o[(16 * w + 4 * lq + r) * 64 + 16 * n + l15] = st[n][r];
}

// ---------------------------------------------------------------------------
// out0_ds1 (512 threads, 8 waves): GLA output chunk + dS1 + EbT emission.
// wave = (tw = w>>1 : t/d-tile, eh = w&1 : e/c-half). 2 fragments per wave.
// ---------------------------------------------------------------------------
__global__ __launch_bounds__(512) void out0_ds1(const float* __restrict__ x,
                                                const ushort_t* __restrict__ Qb,
                                                const ushort_t* __restrict__ Kb,
                                                const ushort_t* __restrict__ K2b,
                                                const float* __restrict__ gc,
                                                const float* __restrict__ ab,
                                                const float* __restrict__ dS0,
                                                float* __restrict__ O1out,
                                                float* __restrict__ dS1,
                                                ushort_t* __restrict__ EbT) {
    const int rt = blockIdx.x, bh = blockIdx.y;
    const int b = bh >> 4, h = bh & 15;
    const int c0 = rt * 64;
    const int tid = threadIdx.x;
    const int w = tid >> 6, lane = tid & 63;
    const int l15 = lane & 15, lq = lane >> 4;
    const int tw = w >> 1, eh = w & 1;

    __shared__ __align__(16) char Qs[8192];
    __shared__ __align__(16) char Ks[8192];
    __shared__ ushort_t VT[64][72];
    __shared__ ushort_t K2T[64][72];
    __shared__ ushort_t ET[64][72];
    __shared__ ushort_t Ps[64][72];
    __shared__ ushort_t SBt[64][72];
    __shared__ float av[64], gcv[64];

    const size_t base = (size_t)(b * 512) * 1024 + h * 64;
    const size_t rowB = (size_t)(b * 512 + c0) * 2048 + h * 128;

    {
        const int p = tid * 16;
        const int row = p >> 7;
        const int scb = (p & 127) ^ ((row & 7) << 4);
        gl16((const char*)Qb + rowB + (size_t)row * 2048 + scb, Qs + w * 1024);
        gl16((const char*)Kb + rowB + (size_t)row * 2048 + scb, Ks + w * 1024);
    }
#pragma unroll
    for (int it = 0; it < 2; ++it) {
        const int idx = tid + it * 512;
        const int rr = idx >> 4;
        const int c4 = (idx & 15) << 2;
        const int tau = c0 + rr;
        float4 xv = *reinterpret_cast<const float4*>(x + base + (size_t)tau * 1024 + c4);
        VT[c4 + 0][rr] = f2bf(xv.x); VT[c4 + 1][rr] = f2bf(xv.y);
        VT[c4 + 2][rr] = f2bf(xv.z); VT[c4 + 3][rr] = f2bf(xv.w);
        ushort4 cv = *reinterpret_cast<const ushort4*>(K2b + base + (size_t)tau * 1024 + c4);
        K2T[c4 + 0][rr] = cv.x; K2T[c4 + 1][rr] = cv.y;
        K2T[c4 + 2][rr] = cv.z; K2T[c4 + 3][rr] = cv.w;
    }
    if (tid < 64) av[tid] = ab[bh * 512 + c0 + tid];
    else if (tid < 128) gcv[tid - 64] = gc[bh * 512 + c0 + tid - 64];

#pragma unroll
    for (int ii = 0; ii < 2; ++ii) {
        const int flat = tid * 8 + ii * 4;
        float4 s = {0.f, 0.f, 0.f, 0.f};
        for (int jj = 0; jj < rt; ++jj) {
            float4 v = *reinterpret_cast<const float4*>(dS0 + (size_t)(bh * 8 + jj) * 4096 + flat);
            s.x += v.x; s.y += v.y; s.z += v.z; s.w += v.w;
        }
        const int d = flat >> 6, e = flat & 63;
        SBt[e + 0][d] = f2bf(s.x); SBt[e + 1][d] = f2bf(s.y);
        SBt[e + 2][d] = f2bf(s.z); SBt[e + 3][d] = f2bf(s.w);
    }
    __syncthreads();

    const int ra = 16 * tw + l15;
    f32x4 sc[2];
    sc[0] = (f32x4){0.f, 0.f, 0.f, 0.f};
    sc[1] = (f32x4){0.f, 0.f, 0.f, 0.f};
#pragma unroll
    for (int kk = 0; kk < 64; kk += 32) {
        const int cb = (kk + 8 * lq) * 2;
        bf16x8 aq = *reinterpret_cast<const bf16x8*>(Qs + ra * 128 + (cb ^ ((ra & 7) << 4)));
#pragma unroll
        for (int i = 0; i < 2; ++i) {
            const int rb = 16 * (2 * eh + i) + l15;
            bf16x8 bb = *reinterpret_cast<const bf16x8*>(Ks + rb * 128 + (cb ^ ((rb & 7) << 4)));
            sc[i] = __builtin_amdgcn_mfma_f32_16x16x32_bf16(aq, bb, sc[i], 0, 0, 0);
        }
    }
#pragma unroll
    for (int i = 0; i < 2; ++i) {
        const int cl = 16 * (2 * eh + i) + l15;
#pragma unroll
        for (int r = 0; r < 4; ++r) {
            const int tl = 16 * tw + 4 * lq + r;
            Ps[tl][cl] = f2bf(cl <= tl ? sc[i][r] * av[cl] : 0.f);
        }
    }
    __syncthreads();

    f32x4 oc[2];
    oc[0] = (f32x4){0.f, 0.f, 0.f, 0.f};
    oc[1] = (f32x4){0.f, 0.f, 0.f, 0.f};
#pragma unroll
    for (int kk = 0; kk < 64; kk += 32) {
        const int cb = (kk + 8 * lq) * 2;
        bf16x8 aq = *reinterpret_cast<const bf16x8*>(Qs + ra * 128 + (cb ^ ((ra & 7) << 4)));
        bf16x8 ap = *reinterpret_cast<const bf16x8*>(&Ps[16 * tw + l15][kk + 8 * lq]);
#pragma unroll
        for (int i = 0; i < 2; ++i) {
            const int nb = 16 * (2 * eh + i) + l15;
            bf16x8 sb = *reinterpret_cast<const bf16x8*>(&SBt[nb][kk + 8 * lq]);
            oc[i] = __builtin_amdgcn_mfma_f32_16x16x32_bf16(aq, sb, oc[i], 0, 0, 0);
            bf16x8 vb = *reinterpret_cast<const bf16x8*>(&VT[nb][kk + 8 * lq]);
            oc[i] = __builtin_amdgcn_mfma_f32_16x16x32_bf16(ap, vb, oc[i], 0, 0, 0);
        }
    }

#pragma unroll
    for (int i = 0; i < 2; ++i) {
        const int e = 16 * (2 * eh + i) + l15;
#pragma unroll
        for (int r = 0; r < 4; ++r) {
            const int tl = 16 * tw + 4 * lq + r;
            const int tau = c0 + tl;
            const float val = gcv[tl] * oc[i][r];
            O1out[base + (size_t)tau * 1024 + e] = val;
            float ev = 0.f;
            if (tau <= 510) ev = x[base + (size_t)(tau + 1) * 1024 + e] - val;
            ET[e][tl] = f2bf(ev);
        }
    }
    __syncthreads();

    {
        const int e = tid >> 3;
        const int tq = (tid & 7) * 8;
        uint4 v0 = *reinterpret_cast<const uint4*>(&ET[e][tq]);
        *reinterpret_cast<uint4*>(EbT + (size_t)(bh * 64 + e) * 512 + c0 + tq) = v0;
    }

    f32x4 st[2];
    st[0] = (f32x4){0.f, 0.f, 0.f, 0.f};
    st[1] = (f32x4){0.f, 0.f, 0.f, 0.f};
#pragma unroll
    for (int kk = 0; kk < 64; kk += 32) {
        bf16x8 ak = *reinterpret_cast<const bf16x8*>(&K2T[16 * tw + l15][kk + 8 * lq]);
#pragma unroll
        for (int i = 0; i < 2; ++i) {
            bf16x8 eb = *reinterpret_cast<const bf16x8*>(&ET[16 * (2 * eh + i) + l15][kk + 8 * lq]);
            st[i] = __builtin_amdgcn_mfma_f32_16x16x32_bf16(ak, eb, st[i], 0, 0, 0);
        }
    }
    float* o = dS1 + (size_t)(bh * 8 + rt) * 4096;
#pragma unroll
    for (int i = 0; i < 2; ++i)
#pragma unroll
        for (int r = 0; r < 4; ++r)
            o[(16 * tw + 4 * lq + r) * 64 + 16 * (2 * eh + i) + l15] = st[i][r];
}

// ---------------------------------------------------------------------------
// out1 (512 threads): MA-branch output + final y in bf16.
// ---------------------------------------------------------------------------
__global__ __launch_bounds__(512) void out1_k(const ushort_t* __restrict__ Q2b,
                                              const ushort_t* __restrict__ K2b,
                                              const ushort_t* __restrict__ EbT,
                                              const float* __restrict__ O1,
                                              const float* __restrict__ dS1,
                                              ushort_t* __restrict__ yout) {
    const int rt = blockIdx.x, bh = blockIdx.y;
    const int b = bh >> 4, h = bh & 15;
    const int c0 = rt * 64;
    const int tid = threadIdx.x;
    const int w = tid >> 6, lane = tid & 63;
    const int l15 = lane & 15, lq = lane >> 4;
    const int tw = w >> 1, eh = w & 1;

    __shared__ __align__(16) char Q2s[8192];
    __shared__ __align__(16) char K2s[8192];
    __shared__ __align__(16) char ETs[8192];
    __shared__ ushort_t Ps[64][72];
    __shared__ ushort_t SBt[64][72];

    const size_t base = (size_t)(b * 512) * 1024 + h * 64;
    const size_t rowB = (size_t)(b * 512 + c0) * 2048 + h * 128;

    {
        const int p = tid * 16;
        const int row = p >> 7;
        const int scb = (p & 127) ^ ((row & 7) << 4);
        gl16((const char*)Q2b + rowB + (size_t)row * 2048 + scb, Q2s + w * 1024);
        gl16((const char*)K2b + rowB + (size_t)row * 2048 + scb, K2s + w * 1024);
        gl16((const char*)EbT + (size_t)(bh * 64 + row) * 1024 + c0 * 2 + scb, ETs + w * 1024);
    }
#pragma unroll
    for (int ii = 0; ii < 2; ++ii) {
        const int flat = tid * 8 + ii * 4;
        float4 s = {0.f, 0.f, 0.f, 0.f};
        for (int jj = 0; jj < rt; ++jj) {
            float4 v = *reinterpret_cast<const float4*>(dS1 + (size_t)(bh * 8 + jj) * 4096 + flat);
            s.x += v.x; s.y += v.y; s.z += v.z; s.w += v.w;
        }
        const int d = flat >> 6, e = flat & 63;
        SBt[e + 0][d] = f2bf(s.x); SBt[e + 1][d] = f2bf(s.y);
        SBt[e + 2][d] = f2bf(s.z); SBt[e + 3][d] = f2bf(s.w);
    }
    __syncthreads();

    const int ra = 16 * tw + l15;
    f32x4 sc[2];
    sc[0] = (f32x4){0.f, 0.f, 0.f, 0.f};
    sc[1] = (f32x4){0.f, 0.f, 0.f, 0.f};
#pragma unroll
    for (int kk = 0; kk < 64; kk += 32) {
        const int cb = (kk + 8 * lq) * 2;
        bf16x8 aq = *reinterpret_cast<const bf16x8*>(Q2s + ra * 128 + (cb ^ ((ra & 7) << 4)));
#pragma unroll
        for (int i = 0; i < 2; ++i) {
            const int rb = 16 * (2 * eh + i) + l15;
            bf16x8 bb = *reinterpret_cast<const bf16x8*>(K2s + rb * 128 + (cb ^ ((rb & 7) << 4)));
            sc[i] = __builtin_amdgcn_mfma_f32_16x16x32_bf16(aq, bb, sc[i], 0, 0, 0);
        }
    }
#pragma unroll
    for (int i = 0; i < 2; ++i) {
        const int cl = 16 * (2 * eh + i) + l15;
#pragma unroll
        for (int r = 0; r < 4; ++r) {
            const int tl = 16 * tw + 4 * lq + r;
            Ps[tl][cl] = f2bf(cl <= tl ? sc[i][r] : 0.f);
        }
    }
    __syncthreads();

    f32x4 oc[2];
    oc[0] = (f32x4){0.f, 0.f, 0.f, 0.f};
    oc[1] = (f32x4){0.f, 0.f, 0.f, 0.f};
#pragma unroll
    for (int kk = 0; kk < 64; kk += 32) {
        const int cb = (kk + 8 * lq) * 2;
        bf16x8 aq = *reinterpret_cast<const bf16x8*>(Q2s + ra * 128 + (cb ^ ((ra & 7) << 4)));
        bf16x8 ap = *reinterpret_cast<const bf16x8*>(&Ps[16 * tw + l15][kk + 8 * lq]);
#pragma unroll
        for (int i = 0; i < 2; ++i) {
            const int rb = 16 * (2 * eh + i) + l15;
            bf16x8 sb = *reinterpret_cast<const bf16x8*>(&SBt[rb][kk + 8 * lq]);
            oc[i] = __builtin_amdgcn_mfma_f32_16x16x32_bf16(aq, sb, oc[i], 0, 0, 0);
            bf16x8 eb = *reinterpret_cast<const bf16x8*>(ETs + rb * 128 + (cb ^ ((rb & 7) << 4)));
            oc[i] = __builtin_amdgcn_mfma_f32_16x16x32_bf16(ap, eb, oc[i], 0, 0, 0);
        }
    }

#pragma unroll
    for (int i = 0; i < 2; ++i) {
        const int e = 16 * (2 * eh + i) + l15;
#pragma unroll
        for (int r = 0; r < 4; ++r) {
            const int tp = c0 + 16 * tw + 4 * lq + r;
            if (tp <= 510) {
                yout[(size_t)(b * 512 + tp + 1) * 1024 + h * 64 + e] =
                    f2bf(O1[base + (size_t)(tp + 1) * 1024 + e] + oc[i][r]);
            }
        }
    }
    if (rt == 0 && tid < 64)
        yout[(size_t)(b * 512) * 1024 + h * 64 + tid] = f2bf(O1[base + tid]);
}

// ---------------------------------------------------------------------------
// gemmP (512 threads): final projection, fp32 out, 3-deep counted-vmcnt.
// Per stage: 2 gl16/thread. Steady wait vmcnt(4).
// ---------------------------------------------------------------------------
__global__ __launch_bounds__(512) void gemmP(const ushort_t* __restrict__ Ab,
                                             const ushort_t* __restrict__ WT,
                                             const float* __restrict__ bias,
                                             float* __restrict__ Out) {
    const int m0 = blockIdx.y * 64, n0 = blockIdx.x * 64;
    __shared__ __align__(16) char smem[49152];   // As[3] @0, Bs[3] @24576

    const int tid = threadIdx.x;
    const int w = tid >> 6, lane = tid & 63;
    const int l15 = lane & 15, lq = lane >> 4;
    const int mw = w >> 1, nh = w & 1;

    f32x4 acc[2];
    acc[0] = (f32x4){0.f, 0.f, 0.f, 0.f};
    acc[1] = (f32x4){0.f, 0.f, 0.f, 0.f};

    auto stage = [&](int buf, int k0) {
        const int p = tid * 16;
        const int row = p >> 7;
        const int scb = (p & 127) ^ ((row & 7) << 4);
        gl16((const char*)Ab + (((size_t)(m0 + row)) << 11) + (k0 << 1) + scb,
             smem + buf * 8192 + w * 1024);
        gl16((const char*)WT + (((size_t)(n0 + row)) << 11) + (k0 << 1) + scb,
             smem + 24576 + buf * 8192 + w * 1024);
    };

    stage(0, 0);
    stage(1, 64);
#pragma unroll
    for (int it = 0; it < 16; ++it) {
        const int k0 = it * 64;
        const int cur = it % 3;
        if (it < 14) stage((it + 2) % 3, k0 + 128);
        if (it < 14)      asm volatile("s_waitcnt vmcnt(4)" ::: "memory");
        else if (it == 14) asm volatile("s_waitcnt vmcnt(2)" ::: "memory");
        else               asm volatile("s_waitcnt vmcnt(0)" ::: "memory");
        __builtin_amdgcn_sched_barrier(0);
        __builtin_amdgcn_s_barrier();
        const char* As = smem + cur * 8192;
        const char* Bs = smem + 24576 + cur * 8192;
#pragma unroll
        for (int kk = 0; kk < 64; kk += 32) {
            const int cb = (kk + 8 * lq) * 2;
            const int ra = 16 * mw + l15;
            bf16x8 a = *reinterpret_cast<const bf16x8*>(As + ra * 128 + (cb ^ ((ra & 7) << 4)));
#pragma unroll
            for (int i = 0; i < 2; ++i) {
                const int rb = 16 * (2 * nh + i) + l15;
                bf16x8 b = *reinterpret_cast<const bf16x8*>(Bs + rb * 128 + (cb ^ ((rb & 7) << 4)));
                acc[i] = __builtin_amdgcn_mfma_f32_16x16x32_bf16(a, b, acc[i], 0, 0, 0);
            }
        }
        asm volatile("s_waitcnt lgkmcnt(0)" ::: "memory");
        __builtin_amdgcn_sched_barrier(0);
        __builtin_amdgcn_s_barrier();
    }
#pragma unroll
    for (int i = 0; i < 2; ++i) {
        const int col = n0 + 16 * (2 * nh + i) + l15;
        const float bcol = bias[col];
#pragma unroll
        for (int r = 0; r < 4; ++r) {
            const int row = m0 + 16 * mw + 4 * lq + r;
            Out[(size_t)row * 1024 + col] = acc[i][r] + bcol;
        }
    }
}

// ---------------------------------------------------------------------------
extern "C" void kernel_launch(void* const* d_in, const int* in_sizes, int n_in,
                              void* d_out, int out_size, void* d_ws, size_t ws_size,
                              hipStream_t stream) {
    const float* x   = (const float*)d_in[0];
    const float* q1w = (const float*)d_in[1];
    const float* q1b = (const float*)d_in[2];
    const float* k1w = (const float*)d_in[3];
    const float* k1b = (const float*)d_in[4];
    const float* k2w = (const float*)d_in[5];
    const float* k2b = (const float*)d_in[6];
    const float* gww = (const float*)d_in[7];
    const float* gwb = (const float*)d_in[8];
    const float* sww = (const float*)d_in[9];
    const float* swb = (const float*)d_in[10];
    const float* cpw = (const float*)d_in[11];
    const float* cpb = (const float*)d_in[12];
    float* out = (float*)d_out;

    float* ws = (float*)d_ws;
    float* O1   = ws;                       // 1M floats
    float* dS0b = ws + 1048576;             // 1M
    float* dS1b = ws + 2097152;             // 1M
    float* gcb  = ws + 3145728;             // 16K
    float* abb  = ws + 3162112;             // 16K
    ushort_t* ub = (ushort_t*)(ws + 3178496);
    ushort_t* xb   = ub;                    // 1M ushorts each
    ushort_t* qb   = ub + 1048576;
    ushort_t* q2b  = ub + 2097152;
    ushort_t* kb   = ub + 3145728;
    ushort_t* k2q  = ub + 4194304;
    ushort_t* EbT  = ub + 5242880;
    ushort_t* wqT  = ub + 6291456;
    ushort_t* wkT  = ub + 7340032;
    ushort_t* wcT  = ub + 8388608;
    ushort_t* wpT  = ub + 9437184;
    ushort_t* ytb  = ub + 10485760;
    // end: ~35 MB of d_ws

    cvtT<<<1536, 256, 0, stream>>>(x, q1w, k1w, k2w, cpw, xb, wqT, wkT, wcT, wpT);
    gemmQKC<<<dim3(16, 16, 3), 256, 0, stream>>>(xb, wqT, wkT, wcT, q1b, k1b, k2b,
                                                 x, gww, gwb, sww, swb,
                                                 qb, q2b, kb, k2q, gcb, abb, dS0b);
    out0_ds1<<<dim3(8, 32), 512, 0, stream>>>(x, qb, kb, k2q, gcb, abb, dS0b, O1, dS1b, EbT);
    out1_k<<<dim3(8, 32), 512, 0, stream>>>(q2b, k2q, EbT, O1, dS1b, ytb);
    gemmP<<<dim3(16, 16), 512, 0, stream>>>(ytb, wpT, cpb, out);
}